// Round 3
// baseline (711.560 us; speedup 1.0000x reference)
//
#include <hip/hip_runtime.h>
#include <math.h>

// ---------------------------------------------------------------------------
// GraphSAGE 3-layer forward, bf16-MFMA + LDS-staged edge binning.
//   - CSR build: 2-level binning (bucket = dst>>9, fixed-capacity regions)
//     pass1: LDS-staged scatter of packed 4B records, line-granular flushes
//     pass2: per-bucket local histogram/scan/scatter in LDS, contiguous out
//   - activations bf16; linear = [N x 256] @ [256 x DOUT] bf16 MFMA GEMM
//     with fused bias + L2-norm + ReLU epilogue.
// ---------------------------------------------------------------------------

typedef __attribute__((ext_vector_type(8))) short short8;
typedef __attribute__((ext_vector_type(4))) float f32x4;

#define BSHIFT 9
#define BSIZE 512            // nodes per bucket
#define MAXBUCK 224          // LDS sizing bound (N <= 114688)
#define P1_EDGES 4096        // edges per pass1 block
#define P1_CAP 32            // staging slots per bucket per block
#define CAPB 9216            // edge capacity per bucket region (mean 8163, +11 sigma)

__device__ __forceinline__ unsigned f2bf_rtn(float f) {
    unsigned u = __float_as_uint(f);
    return (u + 0x7fffu + ((u >> 16) & 1u)) >> 16;  // round-to-nearest-even
}

// ---------------- pass 1: bin edges into bucket regions ----------------

__global__ __launch_bounds__(256) void partition_edges(const int* __restrict__ src,
                                                       const int* __restrict__ dst, int E,
                                                       int NBUCK,
                                                       unsigned* __restrict__ recs,
                                                       int* __restrict__ gcnt) {
    __shared__ int cnt[MAXBUCK];
    __shared__ unsigned rec[MAXBUCK * P1_CAP];
    const int tid = threadIdx.x;
    for (int i = tid; i < NBUCK; i += 256) cnt[i] = 0;
    __syncthreads();

    const int base = blockIdx.x * P1_EDGES;
#pragma unroll
    for (int i = 0; i < P1_EDGES / 256; i++) {
        int e = base + i * 256 + tid;
        if (e < E) {
            int s = src[e], d = dst[e];
            int b = d >> BSHIFT;
            unsigned r = ((unsigned)s << BSHIFT) | (unsigned)(d & (BSIZE - 1));
            int pos = atomicAdd(&cnt[b], 1);
            if (pos < P1_CAP) {
                rec[b * P1_CAP + pos] = r;
            } else {  // rare overflow: direct scatter
                int gp = atomicAdd(&gcnt[b], 1);
                if (gp < CAPB) recs[(size_t)b * CAPB + gp] = r;
            }
        }
    }
    __syncthreads();

    // per-wave flush: one cursor atomic + coalesced burst per bucket
    const int wave = tid >> 6, lane = tid & 63;
    for (int b = wave; b < NBUCK; b += 4) {
        int c = min(cnt[b], P1_CAP);
        int gbase = 0;
        if (lane == 0 && c > 0) gbase = atomicAdd(&gcnt[b], c);
        gbase = __shfl(gbase, 0, 64);
        if (lane < c) {
            int gp = gbase + lane;
            if (gp < CAPB) recs[(size_t)b * CAPB + gp] = rec[b * P1_CAP + lane];
        }
    }
}

// ---------------- pass 2: per-bucket local CSR ----------------

__global__ __launch_bounds__(256) void build_local_csr(const unsigned* __restrict__ recs,
                                                       const int* __restrict__ gcnt, int N,
                                                       int* __restrict__ deg,
                                                       int* __restrict__ row_start,
                                                       int* __restrict__ srcs) {
    __shared__ int hist[BSIZE];
    __shared__ int excl[BSIZE];
    __shared__ int cur[BSIZE];
    __shared__ int tscan[256];
    __shared__ int tot0s;
    __shared__ int stage[CAPB];

    const int b = blockIdx.x, tid = threadIdx.x;
    const unsigned* r = recs + (size_t)b * CAPB;
    const int cnt = min(gcnt[b], CAPB);

    hist[tid] = 0;
    hist[tid + 256] = 0;
    __syncthreads();
    for (int i = tid; i < cnt; i += 256) atomicAdd(&hist[r[i] & (BSIZE - 1)], 1);
    __syncthreads();

    // exclusive scan of hist[512] with 256 threads (two halves)
    for (int half = 0; half < 2; half++) {
        int v = hist[half * 256 + tid];
        tscan[tid] = v;
        __syncthreads();
        for (int off = 1; off < 256; off <<= 1) {
            int t = (tid >= off) ? tscan[tid - off] : 0;
            __syncthreads();
            tscan[tid] += t;
            __syncthreads();
        }
        int add = half ? tot0s : 0;
        int ex = tscan[tid] - v + add;
        excl[half * 256 + tid] = ex;
        cur[half * 256 + tid] = ex;
        if (half == 0 && tid == 255) tot0s = tscan[255];
        __syncthreads();
    }

    // scatter src ids into LDS in dst order
    for (int i = tid; i < cnt; i += 256) {
        unsigned rr = r[i];
        int d = rr & (BSIZE - 1);
        int pos = atomicAdd(&cur[d], 1);
        stage[pos] = (int)(rr >> BSHIFT);
    }
    __syncthreads();

    // contiguous stream out
    int* sb = srcs + (size_t)b * CAPB;
    for (int i = tid; i < cnt; i += 256) sb[i] = stage[i];
    const int node0 = b << BSHIFT;
    for (int j = tid; j < BSIZE; j += 256) {
        int node = node0 + j;
        if (node < N) {
            deg[node] = hist[j];
            row_start[node] = b * CAPB + excl[j];
        }
    }
}

// ---------------- fp32 -> bf16 convert (x once per launch) ----------------

__global__ __launch_bounds__(256) void to_bf16(const float* __restrict__ in,
                                               unsigned short* __restrict__ out, int n4) {
    int i = blockIdx.x * blockDim.x + threadIdx.x;
    if (i < n4) {
        float4 v = ((const float4*)in)[i];
        ushort4 o;
        o.x = (unsigned short)f2bf_rtn(v.x);
        o.y = (unsigned short)f2bf_rtn(v.y);
        o.z = (unsigned short)f2bf_rtn(v.z);
        o.w = (unsigned short)f2bf_rtn(v.w);
        ((ushort4*)out)[i] = o;
    }
}

// ---------------- weight pack: [Wl;Wr] -> MFMA B-frag order ----------------

template <int DOUT>
__global__ __launch_bounds__(256) void pack_w(const float* __restrict__ Wl,
                                              const float* __restrict__ Wr,
                                              unsigned short* __restrict__ Bp) {
    constexpr int NT = DOUT / 16;
    int idx = blockIdx.x * blockDim.x + threadIdx.x;
    if (idx >= 8 * NT * 64) return;
    int lane = idx & 63;
    int nt = (idx >> 6) % NT;
    int ks = (idx >> 6) / NT;
    int n = nt * 16 + (lane & 15);
    int k0 = ks * 32 + (lane >> 4) * 8;
    unsigned short v[8];
#pragma unroll
    for (int j = 0; j < 8; j++) {
        int k = k0 + j;
        float w = (k < 128) ? Wl[k * DOUT + n] : Wr[(k - 128) * DOUT + n];
        v[j] = (unsigned short)f2bf_rtn(w);
    }
#pragma unroll
    for (int j = 0; j < 8; j++) Bp[(size_t)idx * 8 + j] = v[j];
}

// ---------------- aggregate: mean of bf16 neighbor rows ----------------
// one wave per node; lane owns 2 channels; 4-deep load pipeline

__global__ __launch_bounds__(256) void aggregate(const unsigned short* __restrict__ h,
                                                 const int* __restrict__ row_start,
                                                 const int* __restrict__ deg,
                                                 const int* __restrict__ srcs,
                                                 unsigned short* __restrict__ mean, int N) {
    int wave = (blockIdx.x * blockDim.x + threadIdx.x) >> 6;
    int lane = threadIdx.x & 63;
    if (wave >= N) return;
    int start = row_start[wave];
    int cnt = deg[wave];
    const unsigned* hp = (const unsigned*)h;
    float a0 = 0.f, b0 = 0.f, a1 = 0.f, b1 = 0.f;
    float a2 = 0.f, b2 = 0.f, a3 = 0.f, b3 = 0.f;
    int e = 0;
    for (; e + 3 < cnt; e += 4) {
        int s0 = srcs[start + e];
        int s1 = srcs[start + e + 1];
        int s2 = srcs[start + e + 2];
        int s3 = srcs[start + e + 3];
        unsigned v0 = hp[(size_t)s0 * 64 + lane];
        unsigned v1 = hp[(size_t)s1 * 64 + lane];
        unsigned v2 = hp[(size_t)s2 * 64 + lane];
        unsigned v3 = hp[(size_t)s3 * 64 + lane];
        a0 += __uint_as_float(v0 << 16);
        b0 += __uint_as_float(v0 & 0xffff0000u);
        a1 += __uint_as_float(v1 << 16);
        b1 += __uint_as_float(v1 & 0xffff0000u);
        a2 += __uint_as_float(v2 << 16);
        b2 += __uint_as_float(v2 & 0xffff0000u);
        a3 += __uint_as_float(v3 << 16);
        b3 += __uint_as_float(v3 & 0xffff0000u);
    }
    for (; e < cnt; e++) {
        unsigned v0 = hp[(size_t)srcs[start + e] * 64 + lane];
        a0 += __uint_as_float(v0 << 16);
        b0 += __uint_as_float(v0 & 0xffff0000u);
    }
    float inv = 1.0f / fmaxf((float)cnt, 1.0f);
    float x = (a0 + a1 + a2 + a3) * inv;
    float y = (b0 + b1 + b2 + b3) * inv;
    unsigned o = f2bf_rtn(x) | (f2bf_rtn(y) << 16);
    ((unsigned*)mean)[(size_t)wave * 64 + lane] = o;
}

// ---------------- MFMA GEMM + bias + L2norm + ReLU ----------------

template <int DOUT, int RELU, int BF16OUT>
__global__ __launch_bounds__(256) void sage_gemm(const unsigned short* __restrict__ meanb,
                                                 const unsigned short* __restrict__ hb,
                                                 const unsigned short* __restrict__ Bp,
                                                 const float* __restrict__ bias,
                                                 void* __restrict__ outp, int N) {
    constexpr int NT = DOUT / 16;
    constexpr int MT = 2;
    __shared__ short Bl[8 * NT * 64 * 8];  // DOUT=128 -> 64KB

    const int tid = threadIdx.x;
    {
        const uint4* s = (const uint4*)Bp;
        uint4* d = (uint4*)Bl;
        constexpr int CNT = 8 * NT * 64;
        for (int i = tid; i < CNT; i += 256) d[i] = s[i];
    }
    __syncthreads();

    const int wave = tid >> 6;
    const int lane = tid & 63;
    const int m = lane & 15;
    const int q = lane >> 4;
    const int rowbase = blockIdx.x * (64 * MT);

    int rowA[MT];
#pragma unroll
    for (int t = 0; t < MT; t++) rowA[t] = rowbase + (wave * MT + t) * 16 + m;

    f32x4 acc[MT][NT];
#pragma unroll
    for (int t = 0; t < MT; t++)
#pragma unroll
        for (int nt = 0; nt < NT; nt++) acc[t][nt] = (f32x4)0.0f;

#pragma unroll
    for (int ks = 0; ks < 8; ks++) {
        const unsigned short* ab = (ks < 4) ? meanb : hb;
        const int koff = (ks & 3) * 32 + q * 8;
        short8 afrag[MT];
#pragma unroll
        for (int t = 0; t < MT; t++) {
            if (rowA[t] < N)
                afrag[t] = *(const short8*)(ab + (size_t)rowA[t] * 128 + koff);
            else
                afrag[t] = (short8)(short)0;
        }
#pragma unroll
        for (int nt = 0; nt < NT; nt++) {
            short8 bfrag = *(const short8*)&Bl[((ks * NT + nt) * 64 + lane) * 8];
#pragma unroll
            for (int t = 0; t < MT; t++)
                acc[t][nt] = __builtin_amdgcn_mfma_f32_16x16x32_bf16(afrag[t], bfrag,
                                                                     acc[t][nt], 0, 0, 0);
        }
    }

    float bs[NT];
#pragma unroll
    for (int nt = 0; nt < NT; nt++) bs[nt] = bias[nt * 16 + m];

#pragma unroll
    for (int t = 0; t < MT; t++) {
        float ss[4] = {0.f, 0.f, 0.f, 0.f};
#pragma unroll
        for (int nt = 0; nt < NT; nt++)
#pragma unroll
            for (int r = 0; r < 4; r++) {
                acc[t][nt][r] += bs[nt];
                ss[r] += acc[t][nt][r] * acc[t][nt][r];
            }
#pragma unroll
        for (int msk = 1; msk < 16; msk <<= 1)
#pragma unroll
            for (int r = 0; r < 4; r++) ss[r] += __shfl_xor(ss[r], msk, 64);
        float rinv[4];
#pragma unroll
        for (int r = 0; r < 4; r++) rinv[r] = 1.0f / fmaxf(sqrtf(ss[r]), 1e-12f);

#pragma unroll
        for (int r = 0; r < 4; r++) {
            int row = rowbase + (wave * MT + t) * 16 + q * 4 + r;
            if (row < N) {
#pragma unroll
                for (int nt = 0; nt < NT; nt++) {
                    float v = acc[t][nt][r] * rinv[r];
                    if (RELU) v = fmaxf(v, 0.0f);
                    int col = nt * 16 + m;
                    if (BF16OUT)
                        ((unsigned short*)outp)[(size_t)row * DOUT + col] =
                            (unsigned short)f2bf_rtn(v);
                    else
                        ((float*)outp)[(size_t)row * DOUT + col] = v;
                }
            }
        }
    }
}

static inline size_t align_up(size_t x, size_t a) { return (x + a - 1) & ~(a - 1); }

extern "C" void kernel_launch(void* const* d_in, const int* in_sizes, int n_in,
                              void* d_out, int out_size, void* d_ws, size_t ws_size,
                              hipStream_t stream) {
    const int N = in_sizes[0] / 128;
    const int E = in_sizes[1] / 2;
    const int NBUCK = (N + BSIZE - 1) >> BSHIFT;  // 196 for N=100000

    const float* x = (const float*)d_in[0];
    const int* ei = (const int*)d_in[1];
    const int* src = ei;
    const int* dst = ei + E;
    const float* Wl0 = (const float*)d_in[2];
    const float* bl0 = (const float*)d_in[3];
    const float* Wr0 = (const float*)d_in[4];
    const float* Wl1 = (const float*)d_in[5];
    const float* bl1 = (const float*)d_in[6];
    const float* Wr1 = (const float*)d_in[7];
    const float* Wl2 = (const float*)d_in[8];
    const float* bl2 = (const float*)d_in[9];
    const float* Wr2 = (const float*)d_in[10];
    float* out = (float*)d_out;

    // workspace carve-up
    char* w = (char*)d_ws;
    int* deg = (int*)w;                 w += align_up((size_t)N * 4, 256);
    int* row_start = (int*)w;           w += align_up((size_t)N * 4, 256);
    int* gcnt = (int*)w;                w += align_up((size_t)MAXBUCK * 4, 256);
    unsigned* recs = (unsigned*)w;      w += align_up((size_t)NBUCK * CAPB * 4, 256);
    int* srcs = (int*)w;                w += align_up((size_t)NBUCK * CAPB * 4, 256);
    unsigned short* xbf = (unsigned short*)w;   w += align_up((size_t)N * 128 * 2, 256);
    unsigned short* hA = (unsigned short*)w;    w += align_up((size_t)N * 128 * 2, 256);
    unsigned short* hB = (unsigned short*)w;    w += align_up((size_t)N * 128 * 2, 256);
    unsigned short* meanb = (unsigned short*)w; w += align_up((size_t)N * 128 * 2, 256);
    unsigned short* Bp0 = (unsigned short*)w;   w += align_up(8 * 8 * 64 * 8 * 2, 256);
    unsigned short* Bp1 = (unsigned short*)w;   w += align_up(8 * 8 * 64 * 8 * 2, 256);
    unsigned short* Bp2 = (unsigned short*)w;   w += align_up(8 * 4 * 64 * 8 * 2, 256);

    // ---- CSR build (2-level binning) + conversions/packs ----
    hipMemsetAsync(gcnt, 0, (size_t)NBUCK * 4, stream);
    partition_edges<<<(E + P1_EDGES - 1) / P1_EDGES, 256, 0, stream>>>(src, dst, E, NBUCK,
                                                                       recs, gcnt);
    to_bf16<<<(N * 32 + 255) / 256, 256, 0, stream>>>(x, xbf, N * 32);
    pack_w<128><<<(8 * 8 * 64 + 255) / 256, 256, 0, stream>>>(Wl0, Wr0, Bp0);
    pack_w<128><<<(8 * 8 * 64 + 255) / 256, 256, 0, stream>>>(Wl1, Wr1, Bp1);
    pack_w<64><<<(8 * 4 * 64 + 255) / 256, 256, 0, stream>>>(Wl2, Wr2, Bp2);
    build_local_csr<<<NBUCK, 256, 0, stream>>>(recs, gcnt, N, deg, row_start, srcs);

    const int aggGrid = (N + 3) / 4;       // 4 waves/block, 1 node/wave
    const int gemmGrid = (N + 127) / 128;  // 128 rows/block

    // ---- layer 0: x -> hA (relu, bf16 out) ----
    aggregate<<<aggGrid, 256, 0, stream>>>(xbf, row_start, deg, srcs, meanb, N);
    sage_gemm<128, 1, 1><<<gemmGrid, 256, 0, stream>>>(meanb, xbf, Bp0, bl0, hA, N);

    // ---- layer 1: hA -> hB (relu, bf16 out) ----
    aggregate<<<aggGrid, 256, 0, stream>>>(hA, row_start, deg, srcs, meanb, N);
    sage_gemm<128, 1, 1><<<gemmGrid, 256, 0, stream>>>(meanb, hA, Bp1, bl1, hB, N);

    // ---- layer 2: hB -> out (no relu, fp32 out) ----
    aggregate<<<aggGrid, 256, 0, stream>>>(hB, row_start, deg, srcs, meanb, N);
    sage_gemm<64, 0, 0><<<gemmGrid, 256, 0, stream>>>(meanb, hB, Bp2, bl2, out, N);
}

// Round 4
// 450.297 us; speedup vs baseline: 1.5802x; 1.5802x over previous
//
#include <hip/hip_runtime.h>
#include <math.h>

// ---------------------------------------------------------------------------
// GraphSAGE 3-layer forward, bf16-MFMA + LDS-staged edge binning (v2).
//   - pass1: bin edges into 512-node bucket regions; per-bucket LDS staging,
//     PARALLEL per-bucket cursor atomics (padded to 64B lines), cooperative
//     slot-strided flush (no dependent atomic chains).
//   - pass2: per HALF-bucket local histogram/scan/scatter in LDS.
//   - activations bf16; linear = [N x 256] @ [256 x DOUT] bf16 MFMA GEMM
//     with fused bias + L2-norm + ReLU epilogue.
// ---------------------------------------------------------------------------

typedef __attribute__((ext_vector_type(8))) short short8;
typedef __attribute__((ext_vector_type(4))) float f32x4;

#define BSHIFT 9
#define BSIZE 512            // nodes per bucket
#define MAXBUCK 224          // LDS sizing bound (N <= 114688)
#define P1_EDGES 4096        // edges per pass1 block
#define P1_CAP 64            // staging slots per bucket per block (mean ~21)
#define CAPB 9216            // edge capacity per bucket region (mean 8163, +11 sigma)
#define CAPH 5376            // stage capacity per half-bucket (mean ~4082)
#define GPAD 16              // gcnt padding: one counter per 64B line

__device__ __forceinline__ unsigned f2bf_rtn(float f) {
    unsigned u = __float_as_uint(f);
    return (u + 0x7fffu + ((u >> 16) & 1u)) >> 16;  // round-to-nearest-even
}

// ---------------- pass 1: bin edges into bucket regions ----------------

__global__ __launch_bounds__(256) void partition_edges(const int* __restrict__ src,
                                                       const int* __restrict__ dst, int E,
                                                       int NBUCK,
                                                       unsigned* __restrict__ recs,
                                                       int* __restrict__ gcntp) {
    __shared__ int cnt[MAXBUCK];
    __shared__ int basem[MAXBUCK];
    __shared__ unsigned rec[MAXBUCK * P1_CAP];  // 56 KB
    const int tid = threadIdx.x;
    for (int i = tid; i < NBUCK; i += 256) cnt[i] = 0;
    __syncthreads();

    const int base = blockIdx.x * P1_EDGES;
#pragma unroll
    for (int i = 0; i < P1_EDGES / 256; i++) {
        int e = base + i * 256 + tid;
        if (e < E) {
            int s = src[e], d = dst[e];
            int b = d >> BSHIFT;
            unsigned r = ((unsigned)s << BSHIFT) | (unsigned)(d & (BSIZE - 1));
            int pos = atomicAdd(&cnt[b], 1);
            if (pos < P1_CAP) {
                rec[(b << 6) + pos] = r;
            } else {  // very rare overflow: direct reserve
                int gp = atomicAdd(&gcntp[b * GPAD], 1);
                if (gp < CAPB) recs[(size_t)b * CAPB + gp] = r;
            }
        }
    }
    __syncthreads();

    // parallel per-bucket reservation: one atomic per bucket, distinct lines
    for (int b = tid; b < NBUCK; b += 256) {
        int c = min(cnt[b], P1_CAP);
        cnt[b] = c;
        basem[b] = (c > 0) ? atomicAdd(&gcntp[b * GPAD], c) : 0;
    }
    __syncthreads();

    // cooperative flush: slot-strided, independent stores
    const int slots = NBUCK << 6;
    for (int s = tid; s < slots; s += 256) {
        int b = s >> 6, i = s & 63;
        if (i < cnt[b]) {
            int gp = basem[b] + i;
            if (gp < CAPB) recs[(size_t)b * CAPB + gp] = rec[s];
        }
    }
}

// ---------------- pass 2: per half-bucket local CSR ----------------

__global__ __launch_bounds__(256) void build_local_csr(const unsigned* __restrict__ recs,
                                                       const int* __restrict__ gcntp, int N,
                                                       int* __restrict__ deg,
                                                       int* __restrict__ row_start,
                                                       int* __restrict__ srcs) {
    __shared__ int hist[256];
    __shared__ int excl[256];
    __shared__ int cur[256];
    __shared__ int tscan[256];
    __shared__ int c0tot;
    __shared__ int stage[CAPH];

    const int tid = threadIdx.x;
    const int b = blockIdx.x >> 1;
    const int half = blockIdx.x & 1;
    const unsigned* r = recs + (size_t)b * CAPB;
    const int cnt = min(gcntp[b * GPAD], CAPB);

    hist[tid] = 0;
    if (tid == 0) c0tot = 0;
    __syncthreads();

    int my0 = 0;
    for (int i = tid; i < cnt; i += 256) {
        unsigned rr = r[i];
        int d = rr & (BSIZE - 1);
        if (d < 256) my0++;
        if ((d >> 8) == half) atomicAdd(&hist[d & 255], 1);
    }
    // wave-reduce my0, then one LDS atomic per wave
#pragma unroll
    for (int off = 32; off > 0; off >>= 1) my0 += __shfl_down(my0, off, 64);
    if ((tid & 63) == 0) atomicAdd(&c0tot, my0);
    __syncthreads();

    // exclusive scan of hist[256]
    int v = hist[tid];
    tscan[tid] = v;
    __syncthreads();
    for (int off = 1; off < 256; off <<= 1) {
        int t = (tid >= off) ? tscan[tid - off] : 0;
        __syncthreads();
        tscan[tid] += t;
        __syncthreads();
    }
    int ex = tscan[tid] - v;
    excl[tid] = ex;
    cur[tid] = ex;
    __syncthreads();

    // scatter my half's src ids into LDS in dst order
    for (int i = tid; i < cnt; i += 256) {
        unsigned rr = r[i];
        int d = rr & (BSIZE - 1);
        if ((d >> 8) == half) {
            int pos = atomicAdd(&cur[d & 255], 1);
            if (pos < CAPH) stage[pos] = (int)(rr >> BSHIFT);
        }
    }
    __syncthreads();

    const int gbase = half ? c0tot : 0;
    int myCnt = min(excl[255] + hist[255], CAPH);
    int* sb = srcs + (size_t)b * CAPB + gbase;
    for (int i = tid; i < myCnt; i += 256) sb[i] = stage[i];
    const int node = (b << BSHIFT) + half * 256 + tid;
    if (node < N) {
        deg[node] = hist[tid];
        row_start[node] = b * CAPB + gbase + excl[tid];
    }
}

// ---------------- fp32 -> bf16 convert (x once per launch) ----------------

__global__ __launch_bounds__(256) void to_bf16(const float* __restrict__ in,
                                               unsigned short* __restrict__ out, int n4) {
    int i = blockIdx.x * blockDim.x + threadIdx.x;
    if (i < n4) {
        float4 v = ((const float4*)in)[i];
        ushort4 o;
        o.x = (unsigned short)f2bf_rtn(v.x);
        o.y = (unsigned short)f2bf_rtn(v.y);
        o.z = (unsigned short)f2bf_rtn(v.z);
        o.w = (unsigned short)f2bf_rtn(v.w);
        ((ushort4*)out)[i] = o;
    }
}

// ---------------- weight pack: [Wl;Wr] -> MFMA B-frag order ----------------

template <int DOUT>
__global__ __launch_bounds__(256) void pack_w(const float* __restrict__ Wl,
                                              const float* __restrict__ Wr,
                                              unsigned short* __restrict__ Bp) {
    constexpr int NT = DOUT / 16;
    int idx = blockIdx.x * blockDim.x + threadIdx.x;
    if (idx >= 8 * NT * 64) return;
    int lane = idx & 63;
    int nt = (idx >> 6) % NT;
    int ks = (idx >> 6) / NT;
    int n = nt * 16 + (lane & 15);
    int k0 = ks * 32 + (lane >> 4) * 8;
    unsigned short v[8];
#pragma unroll
    for (int j = 0; j < 8; j++) {
        int k = k0 + j;
        float w = (k < 128) ? Wl[k * DOUT + n] : Wr[(k - 128) * DOUT + n];
        v[j] = (unsigned short)f2bf_rtn(w);
    }
#pragma unroll
    for (int j = 0; j < 8; j++) Bp[(size_t)idx * 8 + j] = v[j];
}

// ---------------- aggregate: mean of bf16 neighbor rows ----------------

__global__ __launch_bounds__(256) void aggregate(const unsigned short* __restrict__ h,
                                                 const int* __restrict__ row_start,
                                                 const int* __restrict__ deg,
                                                 const int* __restrict__ srcs,
                                                 unsigned short* __restrict__ mean, int N) {
    int wave = (blockIdx.x * blockDim.x + threadIdx.x) >> 6;
    int lane = threadIdx.x & 63;
    if (wave >= N) return;
    int start = row_start[wave];
    int cnt = deg[wave];
    const unsigned* hp = (const unsigned*)h;
    float a0 = 0.f, b0 = 0.f, a1 = 0.f, b1 = 0.f;
    float a2 = 0.f, b2 = 0.f, a3 = 0.f, b3 = 0.f;
    int e = 0;
    for (; e + 3 < cnt; e += 4) {
        int s0 = srcs[start + e];
        int s1 = srcs[start + e + 1];
        int s2 = srcs[start + e + 2];
        int s3 = srcs[start + e + 3];
        unsigned v0 = hp[(size_t)s0 * 64 + lane];
        unsigned v1 = hp[(size_t)s1 * 64 + lane];
        unsigned v2 = hp[(size_t)s2 * 64 + lane];
        unsigned v3 = hp[(size_t)s3 * 64 + lane];
        a0 += __uint_as_float(v0 << 16);
        b0 += __uint_as_float(v0 & 0xffff0000u);
        a1 += __uint_as_float(v1 << 16);
        b1 += __uint_as_float(v1 & 0xffff0000u);
        a2 += __uint_as_float(v2 << 16);
        b2 += __uint_as_float(v2 & 0xffff0000u);
        a3 += __uint_as_float(v3 << 16);
        b3 += __uint_as_float(v3 & 0xffff0000u);
    }
    for (; e < cnt; e++) {
        unsigned v0 = hp[(size_t)srcs[start + e] * 64 + lane];
        a0 += __uint_as_float(v0 << 16);
        b0 += __uint_as_float(v0 & 0xffff0000u);
    }
    float inv = 1.0f / fmaxf((float)cnt, 1.0f);
    float x = (a0 + a1 + a2 + a3) * inv;
    float y = (b0 + b1 + b2 + b3) * inv;
    unsigned o = f2bf_rtn(x) | (f2bf_rtn(y) << 16);
    ((unsigned*)mean)[(size_t)wave * 64 + lane] = o;
}

// ---------------- MFMA GEMM + bias + L2norm + ReLU ----------------

template <int DOUT, int RELU, int BF16OUT>
__global__ __launch_bounds__(256) void sage_gemm(const unsigned short* __restrict__ meanb,
                                                 const unsigned short* __restrict__ hb,
                                                 const unsigned short* __restrict__ Bp,
                                                 const float* __restrict__ bias,
                                                 void* __restrict__ outp, int N) {
    constexpr int NT = DOUT / 16;
    constexpr int MT = 2;
    __shared__ short Bl[8 * NT * 64 * 8];  // DOUT=128 -> 64KB

    const int tid = threadIdx.x;
    {
        const uint4* s = (const uint4*)Bp;
        uint4* d = (uint4*)Bl;
        constexpr int CNT = 8 * NT * 64;
        for (int i = tid; i < CNT; i += 256) d[i] = s[i];
    }
    __syncthreads();

    const int wave = tid >> 6;
    const int lane = tid & 63;
    const int m = lane & 15;
    const int q = lane >> 4;
    const int rowbase = blockIdx.x * (64 * MT);

    int rowA[MT];
#pragma unroll
    for (int t = 0; t < MT; t++) rowA[t] = rowbase + (wave * MT + t) * 16 + m;

    f32x4 acc[MT][NT];
#pragma unroll
    for (int t = 0; t < MT; t++)
#pragma unroll
        for (int nt = 0; nt < NT; nt++) acc[t][nt] = (f32x4)0.0f;

#pragma unroll
    for (int ks = 0; ks < 8; ks++) {
        const unsigned short* ab = (ks < 4) ? meanb : hb;
        const int koff = (ks & 3) * 32 + q * 8;
        short8 afrag[MT];
#pragma unroll
        for (int t = 0; t < MT; t++) {
            if (rowA[t] < N)
                afrag[t] = *(const short8*)(ab + (size_t)rowA[t] * 128 + koff);
            else
                afrag[t] = (short8)(short)0;
        }
#pragma unroll
        for (int nt = 0; nt < NT; nt++) {
            short8 bfrag = *(const short8*)&Bl[((ks * NT + nt) * 64 + lane) * 8];
#pragma unroll
            for (int t = 0; t < MT; t++)
                acc[t][nt] = __builtin_amdgcn_mfma_f32_16x16x32_bf16(afrag[t], bfrag,
                                                                     acc[t][nt], 0, 0, 0);
        }
    }

    float bs[NT];
#pragma unroll
    for (int nt = 0; nt < NT; nt++) bs[nt] = bias[nt * 16 + m];

#pragma unroll
    for (int t = 0; t < MT; t++) {
        float ss[4] = {0.f, 0.f, 0.f, 0.f};
#pragma unroll
        for (int nt = 0; nt < NT; nt++)
#pragma unroll
            for (int r = 0; r < 4; r++) {
                acc[t][nt][r] += bs[nt];
                ss[r] += acc[t][nt][r] * acc[t][nt][r];
            }
#pragma unroll
        for (int msk = 1; msk < 16; msk <<= 1)
#pragma unroll
            for (int r = 0; r < 4; r++) ss[r] += __shfl_xor(ss[r], msk, 64);
        float rinv[4];
#pragma unroll
        for (int r = 0; r < 4; r++) rinv[r] = 1.0f / fmaxf(sqrtf(ss[r]), 1e-12f);

#pragma unroll
        for (int r = 0; r < 4; r++) {
            int row = rowbase + (wave * MT + t) * 16 + q * 4 + r;
            if (row < N) {
#pragma unroll
                for (int nt = 0; nt < NT; nt++) {
                    float v = acc[t][nt][r] * rinv[r];
                    if (RELU) v = fmaxf(v, 0.0f);
                    int col = nt * 16 + m;
                    if (BF16OUT)
                        ((unsigned short*)outp)[(size_t)row * DOUT + col] =
                            (unsigned short)f2bf_rtn(v);
                    else
                        ((float*)outp)[(size_t)row * DOUT + col] = v;
                }
            }
        }
    }
}

static inline size_t align_up(size_t x, size_t a) { return (x + a - 1) & ~(a - 1); }

extern "C" void kernel_launch(void* const* d_in, const int* in_sizes, int n_in,
                              void* d_out, int out_size, void* d_ws, size_t ws_size,
                              hipStream_t stream) {
    const int N = in_sizes[0] / 128;
    const int E = in_sizes[1] / 2;
    const int NBUCK = (N + BSIZE - 1) >> BSHIFT;  // 196 for N=100000

    const float* x = (const float*)d_in[0];
    const int* ei = (const int*)d_in[1];
    const int* src = ei;
    const int* dst = ei + E;
    const float* Wl0 = (const float*)d_in[2];
    const float* bl0 = (const float*)d_in[3];
    const float* Wr0 = (const float*)d_in[4];
    const float* Wl1 = (const float*)d_in[5];
    const float* bl1 = (const float*)d_in[6];
    const float* Wr1 = (const float*)d_in[7];
    const float* Wl2 = (const float*)d_in[8];
    const float* bl2 = (const float*)d_in[9];
    const float* Wr2 = (const float*)d_in[10];
    float* out = (float*)d_out;

    // workspace carve-up
    char* w = (char*)d_ws;
    int* deg = (int*)w;                 w += align_up((size_t)N * 4, 256);
    int* row_start = (int*)w;           w += align_up((size_t)N * 4, 256);
    int* gcntp = (int*)w;               w += align_up((size_t)MAXBUCK * GPAD * 4, 256);
    unsigned* recs = (unsigned*)w;      w += align_up((size_t)NBUCK * CAPB * 4, 256);
    int* srcs = (int*)w;                w += align_up((size_t)NBUCK * CAPB * 4, 256);
    unsigned short* xbf = (unsigned short*)w;   w += align_up((size_t)N * 128 * 2, 256);
    unsigned short* hA = (unsigned short*)w;    w += align_up((size_t)N * 128 * 2, 256);
    unsigned short* hB = (unsigned short*)w;    w += align_up((size_t)N * 128 * 2, 256);
    unsigned short* meanb = (unsigned short*)w; w += align_up((size_t)N * 128 * 2, 256);
    unsigned short* Bp0 = (unsigned short*)w;   w += align_up(8 * 8 * 64 * 8 * 2, 256);
    unsigned short* Bp1 = (unsigned short*)w;   w += align_up(8 * 8 * 64 * 8 * 2, 256);
    unsigned short* Bp2 = (unsigned short*)w;   w += align_up(8 * 4 * 64 * 8 * 2, 256);

    // ---- CSR build (2-level binning) + conversions/packs ----
    hipMemsetAsync(gcntp, 0, (size_t)MAXBUCK * GPAD * 4, stream);
    partition_edges<<<(E + P1_EDGES - 1) / P1_EDGES, 256, 0, stream>>>(src, dst, E, NBUCK,
                                                                       recs, gcntp);
    to_bf16<<<(N * 32 + 255) / 256, 256, 0, stream>>>(x, xbf, N * 32);
    pack_w<128><<<(8 * 8 * 64 + 255) / 256, 256, 0, stream>>>(Wl0, Wr0, Bp0);
    pack_w<128><<<(8 * 8 * 64 + 255) / 256, 256, 0, stream>>>(Wl1, Wr1, Bp1);
    pack_w<64><<<(8 * 4 * 64 + 255) / 256, 256, 0, stream>>>(Wl2, Wr2, Bp2);
    build_local_csr<<<NBUCK * 2, 256, 0, stream>>>(recs, gcntp, N, deg, row_start, srcs);

    const int aggGrid = (N + 3) / 4;       // 4 waves/block, 1 node/wave
    const int gemmGrid = (N + 127) / 128;  // 128 rows/block

    // ---- layer 0: x -> hA (relu, bf16 out) ----
    aggregate<<<aggGrid, 256, 0, stream>>>(xbf, row_start, deg, srcs, meanb, N);
    sage_gemm<128, 1, 1><<<gemmGrid, 256, 0, stream>>>(meanb, xbf, Bp0, bl0, hA, N);

    // ---- layer 1: hA -> hB (relu, bf16 out) ----
    aggregate<<<aggGrid, 256, 0, stream>>>(hA, row_start, deg, srcs, meanb, N);
    sage_gemm<128, 1, 1><<<gemmGrid, 256, 0, stream>>>(meanb, hA, Bp1, bl1, hB, N);

    // ---- layer 2: hB -> out (no relu, fp32 out) ----
    aggregate<<<aggGrid, 256, 0, stream>>>(hB, row_start, deg, srcs, meanb, N);
    sage_gemm<64, 0, 0><<<gemmGrid, 256, 0, stream>>>(meanb, hB, Bp2, bl2, out, N);
}

// Round 5
// 445.734 us; speedup vs baseline: 1.5964x; 1.0102x over previous
//
#include <hip/hip_runtime.h>
#include <math.h>

// ---------------------------------------------------------------------------
// GraphSAGE 3-layer forward, bf16-MFMA + LDS-staged edge binning (v3).
//   - pass1: bin edges into 512-node bucket regions; int4 edge loads,
//     per-bucket LDS staging, parallel padded cursor atomics, uint4 flush.
//   - pass2: per HALF-bucket local histogram/scan/scatter in LDS.
//   - aggregate: 1024-thread blocks (32 waves/CU) + index-prefetch pipeline.
//   - linear = [N x 256] @ [256 x DOUT] bf16 MFMA GEMM, fused bias+L2norm+ReLU.
// ---------------------------------------------------------------------------

typedef __attribute__((ext_vector_type(8))) short short8;
typedef __attribute__((ext_vector_type(4))) float f32x4;

#define BSHIFT 9
#define BSIZE 512            // nodes per bucket
#define MAXBUCK 224          // LDS sizing bound (N <= 114688)
#define P1_EDGES 8192        // edges per pass1 block
#define P1_CAP 64            // staging slots per bucket per block (mean ~42)
#define CAPB 9216            // edge capacity per bucket region (mean 8163)
#define CAPH 5376            // stage capacity per half-bucket (mean ~4082)
#define GPAD 16              // gcnt padding: one counter per 64B line

__device__ __forceinline__ unsigned f2bf_rtn(float f) {
    unsigned u = __float_as_uint(f);
    return (u + 0x7fffu + ((u >> 16) & 1u)) >> 16;  // round-to-nearest-even
}

// ---------------- pass 1: bin edges into bucket regions ----------------

__global__ __launch_bounds__(256) void partition_edges(const int* __restrict__ src,
                                                       const int* __restrict__ dst, int E,
                                                       int NBUCK,
                                                       unsigned* __restrict__ recs,
                                                       int* __restrict__ gcntp) {
    __shared__ int cnt[MAXBUCK];
    __shared__ int basem[MAXBUCK];
    __shared__ unsigned rec[MAXBUCK * P1_CAP];  // 56 KB
    const int tid = threadIdx.x;
    for (int i = tid; i < NBUCK; i += 256) cnt[i] = 0;
    __syncthreads();

    const int base = blockIdx.x * P1_EDGES;
#pragma unroll
    for (int r = 0; r < P1_EDGES / 1024; r++) {
        int e = base + r * 1024 + tid * 4;
        if (e + 3 < E) {
            int4 s4 = *(const int4*)(src + e);
            int4 d4 = *(const int4*)(dst + e);
            int ss[4] = {s4.x, s4.y, s4.z, s4.w};
            int dd[4] = {d4.x, d4.y, d4.z, d4.w};
#pragma unroll
            for (int j = 0; j < 4; j++) {
                int b = dd[j] >> BSHIFT;
                unsigned rr = ((unsigned)ss[j] << BSHIFT) | (unsigned)(dd[j] & (BSIZE - 1));
                int pos = atomicAdd(&cnt[b], 1);
                if (pos < P1_CAP) {
                    rec[(b << 6) + pos] = rr;
                } else {
                    int gp = atomicAdd(&gcntp[b * GPAD], 1);
                    if (gp < CAPB) recs[(size_t)b * CAPB + gp] = rr;
                }
            }
        } else {
            for (int j = 0; j < 4; j++) {
                int ee = e + j;
                if (ee < E) {
                    int s = src[ee], d = dst[ee];
                    int b = d >> BSHIFT;
                    unsigned rr = ((unsigned)s << BSHIFT) | (unsigned)(d & (BSIZE - 1));
                    int pos = atomicAdd(&cnt[b], 1);
                    if (pos < P1_CAP) {
                        rec[(b << 6) + pos] = rr;
                    } else {
                        int gp = atomicAdd(&gcntp[b * GPAD], 1);
                        if (gp < CAPB) recs[(size_t)b * CAPB + gp] = rr;
                    }
                }
            }
        }
    }
    __syncthreads();

    // parallel per-bucket reservation: one atomic per bucket, distinct lines
    for (int b = tid; b < NBUCK; b += 256) {
        int c = min(cnt[b], P1_CAP);
        cnt[b] = c;
        basem[b] = (c > 0) ? atomicAdd(&gcntp[b * GPAD], c) : 0;
    }
    __syncthreads();

    // cooperative flush: thread owns 4 consecutive slots of one bucket
    const int quads = NBUCK << 4;  // NBUCK * 16
    for (int sq = tid; sq < quads; sq += 256) {
        int b = sq >> 4, i0 = (sq & 15) << 2;
        int c = cnt[b];
        if (i0 < c) {
            int gp = basem[b] + i0;
            if (i0 + 3 < c && gp + 3 < CAPB) {
                uint4 v = *(const uint4*)&rec[(b << 6) + i0];
                *(uint4*)&recs[(size_t)b * CAPB + gp] = v;
            } else {
                for (int j = 0; j < 4 && i0 + j < c; j++) {
                    if (gp + j < CAPB) recs[(size_t)b * CAPB + gp + j] = rec[(b << 6) + i0 + j];
                }
            }
        }
    }
}

// ---------------- pass 2: per half-bucket local CSR ----------------

__global__ __launch_bounds__(256) void build_local_csr(const unsigned* __restrict__ recs,
                                                       const int* __restrict__ gcntp, int N,
                                                       int* __restrict__ deg,
                                                       int* __restrict__ row_start,
                                                       int* __restrict__ srcs) {
    __shared__ int hist[256];
    __shared__ int excl[256];
    __shared__ int cur[256];
    __shared__ int tscan[256];
    __shared__ int c0tot;
    __shared__ int stage[CAPH];

    const int tid = threadIdx.x;
    const int b = blockIdx.x >> 1;
    const int half = blockIdx.x & 1;
    const unsigned* r = recs + (size_t)b * CAPB;
    const int cnt = min(gcntp[b * GPAD], CAPB);

    hist[tid] = 0;
    if (tid == 0) c0tot = 0;
    __syncthreads();

    int my0 = 0;
    for (int i = tid; i < cnt; i += 256) {
        unsigned rr = r[i];
        int d = rr & (BSIZE - 1);
        if (d < 256) my0++;
        if ((d >> 8) == half) atomicAdd(&hist[d & 255], 1);
    }
#pragma unroll
    for (int off = 32; off > 0; off >>= 1) my0 += __shfl_down(my0, off, 64);
    if ((tid & 63) == 0) atomicAdd(&c0tot, my0);
    __syncthreads();

    // exclusive scan of hist[256]
    int v = hist[tid];
    tscan[tid] = v;
    __syncthreads();
    for (int off = 1; off < 256; off <<= 1) {
        int t = (tid >= off) ? tscan[tid - off] : 0;
        __syncthreads();
        tscan[tid] += t;
        __syncthreads();
    }
    int ex = tscan[tid] - v;
    excl[tid] = ex;
    cur[tid] = ex;
    __syncthreads();

    // scatter my half's src ids into LDS in dst order
    for (int i = tid; i < cnt; i += 256) {
        unsigned rr = r[i];
        int d = rr & (BSIZE - 1);
        if ((d >> 8) == half) {
            int pos = atomicAdd(&cur[d & 255], 1);
            if (pos < CAPH) stage[pos] = (int)(rr >> BSHIFT);
        }
    }
    __syncthreads();

    const int gbase = half ? c0tot : 0;
    int myCnt = min(excl[255] + hist[255], CAPH);
    int* sb = srcs + (size_t)b * CAPB + gbase;
    for (int i = tid; i < myCnt; i += 256) sb[i] = stage[i];
    const int node = (b << BSHIFT) + half * 256 + tid;
    if (node < N) {
        deg[node] = hist[tid];
        row_start[node] = b * CAPB + gbase + excl[tid];
    }
}

// ---------------- fp32 -> bf16 convert (x once per launch) ----------------

__global__ __launch_bounds__(256) void to_bf16(const float* __restrict__ in,
                                               unsigned short* __restrict__ out, int n4) {
    int i = blockIdx.x * blockDim.x + threadIdx.x;
    if (i < n4) {
        float4 v = ((const float4*)in)[i];
        ushort4 o;
        o.x = (unsigned short)f2bf_rtn(v.x);
        o.y = (unsigned short)f2bf_rtn(v.y);
        o.z = (unsigned short)f2bf_rtn(v.z);
        o.w = (unsigned short)f2bf_rtn(v.w);
        ((ushort4*)out)[i] = o;
    }
}

// ---------------- weight pack: [Wl;Wr] -> MFMA B-frag order ----------------

template <int DOUT>
__global__ __launch_bounds__(256) void pack_w(const float* __restrict__ Wl,
                                              const float* __restrict__ Wr,
                                              unsigned short* __restrict__ Bp) {
    constexpr int NT = DOUT / 16;
    int idx = blockIdx.x * blockDim.x + threadIdx.x;
    if (idx >= 8 * NT * 64) return;
    int lane = idx & 63;
    int nt = (idx >> 6) % NT;
    int ks = (idx >> 6) / NT;
    int n = nt * 16 + (lane & 15);
    int k0 = ks * 32 + (lane >> 4) * 8;
    unsigned short v[8];
#pragma unroll
    for (int j = 0; j < 8; j++) {
        int k = k0 + j;
        float w = (k < 128) ? Wl[k * DOUT + n] : Wr[(k - 128) * DOUT + n];
        v[j] = (unsigned short)f2bf_rtn(w);
    }
#pragma unroll
    for (int j = 0; j < 8; j++) Bp[(size_t)idx * 8 + j] = v[j];
}

// ---------------- aggregate: mean of bf16 neighbor rows ----------------
// 1024-thread blocks (16 waves -> 2 blocks/CU = 32 waves/CU); one wave per
// node; lane owns 2 channels; software-pipelined index prefetch.

__global__ __launch_bounds__(1024) void aggregate(const unsigned short* __restrict__ h,
                                                  const int* __restrict__ row_start,
                                                  const int* __restrict__ deg,
                                                  const int* __restrict__ srcs,
                                                  unsigned short* __restrict__ mean, int N) {
    int node = blockIdx.x * 16 + (threadIdx.x >> 6);
    int lane = threadIdx.x & 63;
    if (node >= N) return;
    int start = row_start[node];
    int cnt = deg[node];
    const unsigned* hp = (const unsigned*)h;
    float a0 = 0.f, b0 = 0.f, a1 = 0.f, b1 = 0.f;
    float a2 = 0.f, b2 = 0.f, a3 = 0.f, b3 = 0.f;

    int n0 = 0, n1 = 0, n2 = 0, n3 = 0;
    if (cnt >= 4) {
        n0 = srcs[start];
        n1 = srcs[start + 1];
        n2 = srcs[start + 2];
        n3 = srcs[start + 3];
    }
    int e = 0;
    for (; e + 3 < cnt;) {
        // issue current gathers
        unsigned v0 = hp[(size_t)n0 * 64 + lane];
        unsigned v1 = hp[(size_t)n1 * 64 + lane];
        unsigned v2 = hp[(size_t)n2 * 64 + lane];
        unsigned v3 = hp[(size_t)n3 * 64 + lane];
        // prefetch next indices (still in flight while we accumulate)
        int m0, m1, m2, m3;
        bool more = (e + 7 < cnt);
        if (more) {
            m0 = srcs[start + e + 4];
            m1 = srcs[start + e + 5];
            m2 = srcs[start + e + 6];
            m3 = srcs[start + e + 7];
        }
        a0 += __uint_as_float(v0 << 16);
        b0 += __uint_as_float(v0 & 0xffff0000u);
        a1 += __uint_as_float(v1 << 16);
        b1 += __uint_as_float(v1 & 0xffff0000u);
        a2 += __uint_as_float(v2 << 16);
        b2 += __uint_as_float(v2 & 0xffff0000u);
        a3 += __uint_as_float(v3 << 16);
        b3 += __uint_as_float(v3 & 0xffff0000u);
        e += 4;
        if (more) {
            n0 = m0; n1 = m1; n2 = m2; n3 = m3;
        }
    }
    for (; e < cnt; e++) {
        unsigned v0 = hp[(size_t)srcs[start + e] * 64 + lane];
        a0 += __uint_as_float(v0 << 16);
        b0 += __uint_as_float(v0 & 0xffff0000u);
    }
    float inv = 1.0f / fmaxf((float)cnt, 1.0f);
    float x = (a0 + a1 + a2 + a3) * inv;
    float y = (b0 + b1 + b2 + b3) * inv;
    unsigned o = f2bf_rtn(x) | (f2bf_rtn(y) << 16);
    ((unsigned*)mean)[(size_t)node * 64 + lane] = o;
}

// ---------------- MFMA GEMM + bias + L2norm + ReLU ----------------

template <int DOUT, int RELU, int BF16OUT>
__global__ __launch_bounds__(256) void sage_gemm(const unsigned short* __restrict__ meanb,
                                                 const unsigned short* __restrict__ hb,
                                                 const unsigned short* __restrict__ Bp,
                                                 const float* __restrict__ bias,
                                                 void* __restrict__ outp, int N) {
    constexpr int NT = DOUT / 16;
    constexpr int MT = 2;
    __shared__ short Bl[8 * NT * 64 * 8];  // DOUT=128 -> 64KB

    const int tid = threadIdx.x;
    {
        const uint4* s = (const uint4*)Bp;
        uint4* d = (uint4*)Bl;
        constexpr int CNT = 8 * NT * 64;
        for (int i = tid; i < CNT; i += 256) d[i] = s[i];
    }
    __syncthreads();

    const int wave = tid >> 6;
    const int lane = tid & 63;
    const int m = lane & 15;
    const int q = lane >> 4;
    const int rowbase = blockIdx.x * (64 * MT);

    int rowA[MT];
#pragma unroll
    for (int t = 0; t < MT; t++) rowA[t] = rowbase + (wave * MT + t) * 16 + m;

    f32x4 acc[MT][NT];
#pragma unroll
    for (int t = 0; t < MT; t++)
#pragma unroll
        for (int nt = 0; nt < NT; nt++) acc[t][nt] = (f32x4)0.0f;

#pragma unroll
    for (int ks = 0; ks < 8; ks++) {
        const unsigned short* ab = (ks < 4) ? meanb : hb;
        const int koff = (ks & 3) * 32 + q * 8;
        short8 afrag[MT];
#pragma unroll
        for (int t = 0; t < MT; t++) {
            if (rowA[t] < N)
                afrag[t] = *(const short8*)(ab + (size_t)rowA[t] * 128 + koff);
            else
                afrag[t] = (short8)(short)0;
        }
#pragma unroll
        for (int nt = 0; nt < NT; nt++) {
            short8 bfrag = *(const short8*)&Bl[((ks * NT + nt) * 64 + lane) * 8];
#pragma unroll
            for (int t = 0; t < MT; t++)
                acc[t][nt] = __builtin_amdgcn_mfma_f32_16x16x32_bf16(afrag[t], bfrag,
                                                                     acc[t][nt], 0, 0, 0);
        }
    }

    float bs[NT];
#pragma unroll
    for (int nt = 0; nt < NT; nt++) bs[nt] = bias[nt * 16 + m];

#pragma unroll
    for (int t = 0; t < MT; t++) {
        float ss[4] = {0.f, 0.f, 0.f, 0.f};
#pragma unroll
        for (int nt = 0; nt < NT; nt++)
#pragma unroll
            for (int r = 0; r < 4; r++) {
                acc[t][nt][r] += bs[nt];
                ss[r] += acc[t][nt][r] * acc[t][nt][r];
            }
#pragma unroll
        for (int msk = 1; msk < 16; msk <<= 1)
#pragma unroll
            for (int r = 0; r < 4; r++) ss[r] += __shfl_xor(ss[r], msk, 64);
        float rinv[4];
#pragma unroll
        for (int r = 0; r < 4; r++) rinv[r] = 1.0f / fmaxf(sqrtf(ss[r]), 1e-12f);

#pragma unroll
        for (int r = 0; r < 4; r++) {
            int row = rowbase + (wave * MT + t) * 16 + q * 4 + r;
            if (row < N) {
#pragma unroll
                for (int nt = 0; nt < NT; nt++) {
                    float v = acc[t][nt][r] * rinv[r];
                    if (RELU) v = fmaxf(v, 0.0f);
                    int col = nt * 16 + m;
                    if (BF16OUT)
                        ((unsigned short*)outp)[(size_t)row * DOUT + col] =
                            (unsigned short)f2bf_rtn(v);
                    else
                        ((float*)outp)[(size_t)row * DOUT + col] = v;
                }
            }
        }
    }
}

static inline size_t align_up(size_t x, size_t a) { return (x + a - 1) & ~(a - 1); }

extern "C" void kernel_launch(void* const* d_in, const int* in_sizes, int n_in,
                              void* d_out, int out_size, void* d_ws, size_t ws_size,
                              hipStream_t stream) {
    const int N = in_sizes[0] / 128;
    const int E = in_sizes[1] / 2;
    const int NBUCK = (N + BSIZE - 1) >> BSHIFT;  // 196 for N=100000

    const float* x = (const float*)d_in[0];
    const int* ei = (const int*)d_in[1];
    const int* src = ei;
    const int* dst = ei + E;
    const float* Wl0 = (const float*)d_in[2];
    const float* bl0 = (const float*)d_in[3];
    const float* Wr0 = (const float*)d_in[4];
    const float* Wl1 = (const float*)d_in[5];
    const float* bl1 = (const float*)d_in[6];
    const float* Wr1 = (const float*)d_in[7];
    const float* Wl2 = (const float*)d_in[8];
    const float* bl2 = (const float*)d_in[9];
    const float* Wr2 = (const float*)d_in[10];
    float* out = (float*)d_out;

    // workspace carve-up
    char* w = (char*)d_ws;
    int* deg = (int*)w;                 w += align_up((size_t)N * 4, 256);
    int* row_start = (int*)w;           w += align_up((size_t)N * 4, 256);
    int* gcntp = (int*)w;               w += align_up((size_t)MAXBUCK * GPAD * 4, 256);
    unsigned* recs = (unsigned*)w;      w += align_up((size_t)NBUCK * CAPB * 4, 256);
    int* srcs = (int*)w;                w += align_up((size_t)NBUCK * CAPB * 4, 256);
    unsigned short* xbf = (unsigned short*)w;   w += align_up((size_t)N * 128 * 2, 256);
    unsigned short* hA = (unsigned short*)w;    w += align_up((size_t)N * 128 * 2, 256);
    unsigned short* hB = (unsigned short*)w;    w += align_up((size_t)N * 128 * 2, 256);
    unsigned short* meanb = (unsigned short*)w; w += align_up((size_t)N * 128 * 2, 256);
    unsigned short* Bp0 = (unsigned short*)w;   w += align_up(8 * 8 * 64 * 8 * 2, 256);
    unsigned short* Bp1 = (unsigned short*)w;   w += align_up(8 * 8 * 64 * 8 * 2, 256);
    unsigned short* Bp2 = (unsigned short*)w;   w += align_up(8 * 4 * 64 * 8 * 2, 256);

    // ---- CSR build (2-level binning) + conversions/packs ----
    hipMemsetAsync(gcntp, 0, (size_t)MAXBUCK * GPAD * 4, stream);
    partition_edges<<<(E + P1_EDGES - 1) / P1_EDGES, 256, 0, stream>>>(src, dst, E, NBUCK,
                                                                       recs, gcntp);
    to_bf16<<<(N * 32 + 255) / 256, 256, 0, stream>>>(x, xbf, N * 32);
    pack_w<128><<<(8 * 8 * 64 + 255) / 256, 256, 0, stream>>>(Wl0, Wr0, Bp0);
    pack_w<128><<<(8 * 8 * 64 + 255) / 256, 256, 0, stream>>>(Wl1, Wr1, Bp1);
    pack_w<64><<<(8 * 4 * 64 + 255) / 256, 256, 0, stream>>>(Wl2, Wr2, Bp2);
    build_local_csr<<<NBUCK * 2, 256, 0, stream>>>(recs, gcntp, N, deg, row_start, srcs);

    const int aggGrid = (N + 15) / 16;     // 16 waves/block, 1 node/wave
    const int gemmGrid = (N + 127) / 128;  // 128 rows/block

    // ---- layer 0: x -> hA (relu, bf16 out) ----
    aggregate<<<aggGrid, 1024, 0, stream>>>(xbf, row_start, deg, srcs, meanb, N);
    sage_gemm<128, 1, 1><<<gemmGrid, 256, 0, stream>>>(meanb, xbf, Bp0, bl0, hA, N);

    // ---- layer 1: hA -> hB (relu, bf16 out) ----
    aggregate<<<aggGrid, 1024, 0, stream>>>(hA, row_start, deg, srcs, meanb, N);
    sage_gemm<128, 1, 1><<<gemmGrid, 256, 0, stream>>>(meanb, hA, Bp1, bl1, hB, N);

    // ---- layer 2: hB -> out (no relu, fp32 out) ----
    aggregate<<<aggGrid, 1024, 0, stream>>>(hB, row_start, deg, srcs, meanb, N);
    sage_gemm<64, 0, 0><<<gemmGrid, 256, 0, stream>>>(meanb, hB, Bp2, bl2, out, N);
}

// Round 6
// 434.960 us; speedup vs baseline: 1.6359x; 1.0248x over previous
//
#include <hip/hip_runtime.h>
#include <math.h>

// ---------------------------------------------------------------------------
// GraphSAGE 3-layer forward (v4).
//   - CSR: 2-level binning; neighbor lists PADDED to x4 with sentinel row N
//     (zero row) so the aggregate runs branchless dwordx4 gathers.
//   - aggregate: lane-group-per-row dwordx4 gathers (4 rows / 128-wide or
//     8 rows / 64-wide per instruction) -> more lines in flight per wave.
//   - layer 2 commuted: z2=[hB@Wl2 | hB@Wr2+b] GEMM first, then 64-wide
//     aggregate of the left half, then add+L2norm epilogue.
// ---------------------------------------------------------------------------

typedef __attribute__((ext_vector_type(8))) short short8;
typedef __attribute__((ext_vector_type(4))) float f32x4;

#define BSHIFT 9
#define BSIZE 512            // nodes per bucket
#define MAXBUCK 224          // LDS sizing bound (N <= 114688)
#define P1_EDGES 8192        // edges per pass1 block
#define P1_CAP 64            // staging slots per bucket per block
#define CAPB 10240           // edge capacity per bucket region (padded lists)
#define CAPH 5888            // stage capacity per half-bucket
#define GPAD 16              // gcnt padding: one counter per 64B line

__device__ __forceinline__ unsigned f2bf_rtn(float f) {
    unsigned u = __float_as_uint(f);
    return (u + 0x7fffu + ((u >> 16) & 1u)) >> 16;  // round-to-nearest-even
}
__device__ __forceinline__ float bf_lo(unsigned v) { return __uint_as_float(v << 16); }
__device__ __forceinline__ float bf_hi(unsigned v) { return __uint_as_float(v & 0xffff0000u); }

// ---------------- pass 1: bin edges into bucket regions ----------------

__global__ __launch_bounds__(256) void partition_edges(const int* __restrict__ src,
                                                       const int* __restrict__ dst, int E,
                                                       int NBUCK,
                                                       unsigned* __restrict__ recs,
                                                       int* __restrict__ gcntp) {
    __shared__ int cnt[MAXBUCK];
    __shared__ int basem[MAXBUCK];
    __shared__ unsigned rec[MAXBUCK * P1_CAP];  // 56 KB
    const int tid = threadIdx.x;
    for (int i = tid; i < NBUCK; i += 256) cnt[i] = 0;
    __syncthreads();

    const int base = blockIdx.x * P1_EDGES;
#pragma unroll
    for (int r = 0; r < P1_EDGES / 1024; r++) {
        int e = base + r * 1024 + tid * 4;
        if (e + 3 < E) {
            int4 s4 = *(const int4*)(src + e);
            int4 d4 = *(const int4*)(dst + e);
            int ss[4] = {s4.x, s4.y, s4.z, s4.w};
            int dd[4] = {d4.x, d4.y, d4.z, d4.w};
#pragma unroll
            for (int j = 0; j < 4; j++) {
                int b = dd[j] >> BSHIFT;
                unsigned rr = ((unsigned)ss[j] << BSHIFT) | (unsigned)(dd[j] & (BSIZE - 1));
                int pos = atomicAdd(&cnt[b], 1);
                if (pos < P1_CAP) {
                    rec[(b << 6) + pos] = rr;
                } else {
                    int gp = atomicAdd(&gcntp[b * GPAD], 1);
                    if (gp < CAPB) recs[(size_t)b * CAPB + gp] = rr;
                }
            }
        } else {
            for (int j = 0; j < 4; j++) {
                int ee = e + j;
                if (ee < E) {
                    int s = src[ee], d = dst[ee];
                    int b = d >> BSHIFT;
                    unsigned rr = ((unsigned)s << BSHIFT) | (unsigned)(d & (BSIZE - 1));
                    int pos = atomicAdd(&cnt[b], 1);
                    if (pos < P1_CAP) {
                        rec[(b << 6) + pos] = rr;
                    } else {
                        int gp = atomicAdd(&gcntp[b * GPAD], 1);
                        if (gp < CAPB) recs[(size_t)b * CAPB + gp] = rr;
                    }
                }
            }
        }
    }
    __syncthreads();

    for (int b = tid; b < NBUCK; b += 256) {
        int c = min(cnt[b], P1_CAP);
        cnt[b] = c;
        basem[b] = (c > 0) ? atomicAdd(&gcntp[b * GPAD], c) : 0;
    }
    __syncthreads();

    const int quads = NBUCK << 4;
    for (int sq = tid; sq < quads; sq += 256) {
        int b = sq >> 4, i0 = (sq & 15) << 2;
        int c = cnt[b];
        if (i0 < c) {
            int gp = basem[b] + i0;
            if (i0 + 3 < c && gp + 3 < CAPB) {
                uint4 v = *(const uint4*)&rec[(b << 6) + i0];
                *(uint4*)&recs[(size_t)b * CAPB + gp] = v;
            } else {
                for (int j = 0; j < 4 && i0 + j < c; j++) {
                    if (gp + j < CAPB) recs[(size_t)b * CAPB + gp + j] = rec[(b << 6) + i0 + j];
                }
            }
        }
    }
}

// ---------------- pass 2: per half-bucket local CSR (padded lists) ----------

__global__ __launch_bounds__(256) void build_local_csr(const unsigned* __restrict__ recs,
                                                       const int* __restrict__ gcntp, int N,
                                                       int* __restrict__ deg,
                                                       int* __restrict__ row_start,
                                                       int* __restrict__ srcs) {
    __shared__ int hist[512];
    __shared__ int excl[512];
    __shared__ int cur[512];
    __shared__ int tscan[256];
    __shared__ int htot0;
    __shared__ int stage[CAPH];

    const int tid = threadIdx.x;
    const int b = blockIdx.x >> 1;
    const int half = blockIdx.x & 1;
    const unsigned* r = recs + (size_t)b * CAPB;
    const int cnt = min(gcntp[b * GPAD], CAPB);

    hist[tid] = 0;
    hist[tid + 256] = 0;
    __syncthreads();
    for (int i = tid; i < cnt; i += 256) atomicAdd(&hist[r[i] & (BSIZE - 1)], 1);
    __syncthreads();

    // exclusive scan over PADDED counts p[j] = (hist[j]+3)&~3, 512 entries
    for (int hs = 0; hs < 2; hs++) {
        int v = (hist[hs * 256 + tid] + 3) & ~3;
        tscan[tid] = v;
        __syncthreads();
        for (int off = 1; off < 256; off <<= 1) {
            int t = (tid >= off) ? tscan[tid - off] : 0;
            __syncthreads();
            tscan[tid] += t;
            __syncthreads();
        }
        int ex = tscan[tid] - v + (hs ? htot0 : 0);
        excl[hs * 256 + tid] = ex;
        cur[hs * 256 + tid] = ex;
        if (hs == 0 && tid == 255) htot0 = tscan[255];
        __syncthreads();
    }

    const int lbase = excl[half * 256];

    // scatter my half's src ids into LDS (positions relative to lbase)
    for (int i = tid; i < cnt; i += 256) {
        unsigned rr = r[i];
        int d = rr & (BSIZE - 1);
        if ((d >> 8) == half) {
            int pos = atomicAdd(&cur[d], 1) - lbase;
            if (pos < CAPH) stage[pos] = (int)(rr >> BSHIFT);
        }
    }
    __syncthreads();

    // pad-fill my half's nodes with sentinel N
    {
        int j = half * 256 + tid;
        int h0 = hist[j];
        int p = (h0 + 3) & ~3;
        int ex = excl[j] - lbase;
        for (int k = h0; k < p; k++)
            if (ex + k < CAPH) stage[ex + k] = N;
    }
    __syncthreads();

    const int last = half * 256 + 255;
    int mycnt = excl[last] + ((hist[last] + 3) & ~3) - lbase;
    mycnt = min(mycnt, CAPH);
    int* sb = srcs + (size_t)b * CAPB + lbase;
    for (int i = tid; i < mycnt; i += 256) sb[i] = stage[i];
    const int node = (b << BSHIFT) + half * 256 + tid;
    if (node < N) {
        deg[node] = hist[half * 256 + tid];
        row_start[node] = b * CAPB + excl[half * 256 + tid];
    }
}

// ---------------- fp32 -> bf16 convert (+ zero sentinel row) ----------------

__global__ __launch_bounds__(256) void to_bf16(const float* __restrict__ in,
                                               unsigned short* __restrict__ out, int n4in,
                                               int n4out) {
    int i = blockIdx.x * blockDim.x + threadIdx.x;
    if (i < n4out) {
        float4 v = {0.f, 0.f, 0.f, 0.f};
        if (i < n4in) v = ((const float4*)in)[i];
        ushort4 o;
        o.x = (unsigned short)f2bf_rtn(v.x);
        o.y = (unsigned short)f2bf_rtn(v.y);
        o.z = (unsigned short)f2bf_rtn(v.z);
        o.w = (unsigned short)f2bf_rtn(v.w);
        ((ushort4*)out)[i] = o;
    }
}

// ---------------- weight packs -> MFMA B-frag order ----------------

template <int DOUT>
__global__ __launch_bounds__(256) void pack_w(const float* __restrict__ Wl,
                                              const float* __restrict__ Wr,
                                              unsigned short* __restrict__ Bp) {
    constexpr int NT = DOUT / 16;
    int idx = blockIdx.x * blockDim.x + threadIdx.x;
    if (idx >= 8 * NT * 64) return;
    int lane = idx & 63;
    int nt = (idx >> 6) % NT;
    int ks = (idx >> 6) / NT;
    int n = nt * 16 + (lane & 15);
    int k0 = ks * 32 + (lane >> 4) * 8;
    unsigned short v[8];
#pragma unroll
    for (int j = 0; j < 8; j++) {
        int k = k0 + j;
        float w = (k < 128) ? Wl[k * DOUT + n] : Wr[(k - 128) * DOUT + n];
        v[j] = (unsigned short)f2bf_rtn(w);
    }
#pragma unroll
    for (int j = 0; j < 8; j++) Bp[(size_t)idx * 8 + j] = v[j];
}

// layer-2 pack: B = [Wl2 | Wr2], K=128, DOUT=128 (4 k-chunks)
__global__ __launch_bounds__(256) void pack_w2(const float* __restrict__ Wl,
                                               const float* __restrict__ Wr,
                                               unsigned short* __restrict__ Bp) {
    int idx = blockIdx.x * blockDim.x + threadIdx.x;
    if (idx >= 4 * 8 * 64) return;
    int lane = idx & 63;
    int nt = (idx >> 6) % 8;
    int ks = (idx >> 6) / 8;
    int n = nt * 16 + (lane & 15);
    int k0 = ks * 32 + (lane >> 4) * 8;
    unsigned short v[8];
#pragma unroll
    for (int j = 0; j < 8; j++) {
        int k = k0 + j;
        float w = (n < 64) ? Wl[k * 64 + n] : Wr[k * 64 + (n - 64)];
        v[j] = (unsigned short)f2bf_rtn(w);
    }
#pragma unroll
    for (int j = 0; j < 8; j++) Bp[(size_t)idx * 8 + j] = v[j];
}

// ---------------- aggregate (128-wide rows): dwordx4, 4 rows/instr ----------

__global__ __launch_bounds__(1024) void aggregate128(const unsigned short* __restrict__ h,
                                                     const int* __restrict__ row_start,
                                                     const int* __restrict__ deg,
                                                     const int* __restrict__ srcs,
                                                     unsigned short* __restrict__ mean,
                                                     int N) {
    int node = blockIdx.x * 16 + (threadIdx.x >> 6);
    if (node >= N) return;
    int lane = threadIdx.x & 63;
    int g = lane >> 4;        // row group 0..3
    int c = lane & 15;        // 16B chunk within row
    int start = row_start[node];
    int cnt = deg[node];
    int pcnt = (cnt + 3) & ~3;
    const uint4* hp = (const uint4*)h;  // 16 uint4 per 128-wide row
    float a[8] = {0.f, 0.f, 0.f, 0.f, 0.f, 0.f, 0.f, 0.f};

    int e = 0;
    for (; e + 7 < pcnt; e += 8) {
        int s0 = srcs[start + e + g];
        int s1 = srcs[start + e + 4 + g];
        uint4 v0 = hp[(size_t)s0 * 16 + c];
        uint4 v1 = hp[(size_t)s1 * 16 + c];
        a[0] += bf_lo(v0.x); a[1] += bf_hi(v0.x);
        a[2] += bf_lo(v0.y); a[3] += bf_hi(v0.y);
        a[4] += bf_lo(v0.z); a[5] += bf_hi(v0.z);
        a[6] += bf_lo(v0.w); a[7] += bf_hi(v0.w);
        a[0] += bf_lo(v1.x); a[1] += bf_hi(v1.x);
        a[2] += bf_lo(v1.y); a[3] += bf_hi(v1.y);
        a[4] += bf_lo(v1.z); a[5] += bf_hi(v1.z);
        a[6] += bf_lo(v1.w); a[7] += bf_hi(v1.w);
    }
    for (; e < pcnt; e += 4) {
        int s0 = srcs[start + e + g];
        uint4 v0 = hp[(size_t)s0 * 16 + c];
        a[0] += bf_lo(v0.x); a[1] += bf_hi(v0.x);
        a[2] += bf_lo(v0.y); a[3] += bf_hi(v0.y);
        a[4] += bf_lo(v0.z); a[5] += bf_hi(v0.z);
        a[6] += bf_lo(v0.w); a[7] += bf_hi(v0.w);
    }
    // reduce the 4 row-groups
#pragma unroll
    for (int i = 0; i < 8; i++) {
        a[i] += __shfl_xor(a[i], 16, 64);
        a[i] += __shfl_xor(a[i], 32, 64);
    }
    if (g == 0) {
        float inv = 1.0f / fmaxf((float)cnt, 1.0f);
        uint4 o;
        o.x = f2bf_rtn(a[0] * inv) | (f2bf_rtn(a[1] * inv) << 16);
        o.y = f2bf_rtn(a[2] * inv) | (f2bf_rtn(a[3] * inv) << 16);
        o.z = f2bf_rtn(a[4] * inv) | (f2bf_rtn(a[5] * inv) << 16);
        o.w = f2bf_rtn(a[6] * inv) | (f2bf_rtn(a[7] * inv) << 16);
        ((uint4*)mean)[(size_t)node * 16 + c] = o;
    }
}

// ---------------- aggregate (64-wide left half of 128-wide z2) --------------

__global__ __launch_bounds__(1024) void aggregate64(const unsigned short* __restrict__ z,
                                                    const int* __restrict__ row_start,
                                                    const int* __restrict__ deg,
                                                    const int* __restrict__ srcs,
                                                    unsigned short* __restrict__ meanz,
                                                    int N) {
    int node = blockIdx.x * 16 + (threadIdx.x >> 6);
    if (node >= N) return;
    int lane = threadIdx.x & 63;
    int g = lane >> 3;        // row group 0..7
    int c = lane & 7;         // 16B chunk within 128B half-row
    int start = row_start[node];
    int cnt = deg[node];
    int pcnt = (cnt + 3) & ~3;
    const uint4* hp = (const uint4*)z;  // 16 uint4 per 128-wide row; left half = first 8
    float a[8] = {0.f, 0.f, 0.f, 0.f, 0.f, 0.f, 0.f, 0.f};

    for (int e = 0; e < pcnt; e += 8) {
        int ee = e + g;
        int s0 = (ee < pcnt) ? srcs[start + ee] : N;  // sentinel zero row
        uint4 v0 = hp[(size_t)s0 * 16 + c];
        a[0] += bf_lo(v0.x); a[1] += bf_hi(v0.x);
        a[2] += bf_lo(v0.y); a[3] += bf_hi(v0.y);
        a[4] += bf_lo(v0.z); a[5] += bf_hi(v0.z);
        a[6] += bf_lo(v0.w); a[7] += bf_hi(v0.w);
    }
#pragma unroll
    for (int i = 0; i < 8; i++) {
        a[i] += __shfl_xor(a[i], 8, 64);
        a[i] += __shfl_xor(a[i], 16, 64);
        a[i] += __shfl_xor(a[i], 32, 64);
    }
    if (g == 0) {
        float inv = 1.0f / fmaxf((float)cnt, 1.0f);
        uint4 o;
        o.x = f2bf_rtn(a[0] * inv) | (f2bf_rtn(a[1] * inv) << 16);
        o.y = f2bf_rtn(a[2] * inv) | (f2bf_rtn(a[3] * inv) << 16);
        o.z = f2bf_rtn(a[4] * inv) | (f2bf_rtn(a[5] * inv) << 16);
        o.w = f2bf_rtn(a[6] * inv) | (f2bf_rtn(a[7] * inv) << 16);
        ((uint4*)meanz)[(size_t)node * 8 + c] = o;
    }
}

// ---------------- layer-2 epilogue: out = L2norm(meanz + z2_right) ----------

__global__ __launch_bounds__(1024) void l2_epilogue(const unsigned short* __restrict__ meanz,
                                                    const unsigned short* __restrict__ z2,
                                                    float* __restrict__ out, int N) {
    int node = blockIdx.x * 16 + (threadIdx.x >> 6);
    if (node >= N) return;
    int lane = threadIdx.x & 63;
    float a = __uint_as_float((unsigned)meanz[(size_t)node * 64 + lane] << 16);
    float b = __uint_as_float((unsigned)z2[(size_t)node * 128 + 64 + lane] << 16);
    float v = a + b;
    float ss = v * v;
#pragma unroll
    for (int off = 32; off > 0; off >>= 1) ss += __shfl_xor(ss, off, 64);
    out[(size_t)node * 64 + lane] = v / fmaxf(sqrtf(ss), 1e-12f);
}

// ---------------- MFMA GEMM + bias (+ optional L2norm/ReLU) ----------------
// KT=8: A=[mean|h] K=256.  KT=4: A=h only, K=128.

template <int KT, int DOUT, int RELU, int NORM, int BF16OUT>
__global__ __launch_bounds__(256) void sage_gemm(const unsigned short* __restrict__ meanb,
                                                 const unsigned short* __restrict__ hb,
                                                 const unsigned short* __restrict__ Bp,
                                                 const float* __restrict__ bias,
                                                 void* __restrict__ outp, int N) {
    constexpr int NT = DOUT / 16;
    constexpr int MT = 2;
    __shared__ short Bl[KT * NT * 64 * 8];

    const int tid = threadIdx.x;
    {
        const uint4* s = (const uint4*)Bp;
        uint4* d = (uint4*)Bl;
        constexpr int CNT = KT * NT * 64;
        for (int i = tid; i < CNT; i += 256) d[i] = s[i];
    }
    __syncthreads();

    const int wave = tid >> 6;
    const int lane = tid & 63;
    const int m = lane & 15;
    const int q = lane >> 4;
    const int rowbase = blockIdx.x * (64 * MT);

    int rowA[MT];
#pragma unroll
    for (int t = 0; t < MT; t++) rowA[t] = rowbase + (wave * MT + t) * 16 + m;

    f32x4 acc[MT][NT];
#pragma unroll
    for (int t = 0; t < MT; t++)
#pragma unroll
        for (int nt = 0; nt < NT; nt++) acc[t][nt] = (f32x4)0.0f;

#pragma unroll
    for (int ks = 0; ks < KT; ks++) {
        const unsigned short* ab = (KT == 8) ? ((ks < 4) ? meanb : hb) : hb;
        const int koff = (KT == 8 ? (ks & 3) : ks) * 32 + q * 8;
        short8 afrag[MT];
#pragma unroll
        for (int t = 0; t < MT; t++) {
            if (rowA[t] < N)
                afrag[t] = *(const short8*)(ab + (size_t)rowA[t] * 128 + koff);
            else
                afrag[t] = (short8)(short)0;
        }
#pragma unroll
        for (int nt = 0; nt < NT; nt++) {
            short8 bfrag = *(const short8*)&Bl[((ks * NT + nt) * 64 + lane) * 8];
#pragma unroll
            for (int t = 0; t < MT; t++)
                acc[t][nt] = __builtin_amdgcn_mfma_f32_16x16x32_bf16(afrag[t], bfrag,
                                                                     acc[t][nt], 0, 0, 0);
        }
    }

    float bs[NT];
#pragma unroll
    for (int nt = 0; nt < NT; nt++) bs[nt] = bias[nt * 16 + m];

#pragma unroll
    for (int t = 0; t < MT; t++) {
        float rinv[4] = {1.f, 1.f, 1.f, 1.f};
#pragma unroll
        for (int nt = 0; nt < NT; nt++)
#pragma unroll
            for (int r = 0; r < 4; r++) acc[t][nt][r] += bs[nt];
        if (NORM) {
            float ss[4] = {0.f, 0.f, 0.f, 0.f};
#pragma unroll
            for (int nt = 0; nt < NT; nt++)
#pragma unroll
                for (int r = 0; r < 4; r++) ss[r] += acc[t][nt][r] * acc[t][nt][r];
#pragma unroll
            for (int msk = 1; msk < 16; msk <<= 1)
#pragma unroll
                for (int r = 0; r < 4; r++) ss[r] += __shfl_xor(ss[r], msk, 64);
#pragma unroll
            for (int r = 0; r < 4; r++) rinv[r] = 1.0f / fmaxf(sqrtf(ss[r]), 1e-12f);
        }

#pragma unroll
        for (int r = 0; r < 4; r++) {
            int row = rowbase + (wave * MT + t) * 16 + q * 4 + r;
            if (row < N) {
#pragma unroll
                for (int nt = 0; nt < NT; nt++) {
                    float v = acc[t][nt][r];
                    if (NORM) v *= rinv[r];
                    if (RELU) v = fmaxf(v, 0.0f);
                    int col = nt * 16 + m;
                    if (BF16OUT)
                        ((unsigned short*)outp)[(size_t)row * DOUT + col] =
                            (unsigned short)f2bf_rtn(v);
                    else
                        ((float*)outp)[(size_t)row * DOUT + col] = v;
                }
            }
        }
    }
}

static inline size_t align_up(size_t x, size_t a) { return (x + a - 1) & ~(a - 1); }

extern "C" void kernel_launch(void* const* d_in, const int* in_sizes, int n_in,
                              void* d_out, int out_size, void* d_ws, size_t ws_size,
                              hipStream_t stream) {
    const int N = in_sizes[0] / 128;
    const int E = in_sizes[1] / 2;
    const int NBUCK = (N + BSIZE - 1) >> BSHIFT;  // 196 for N=100000

    const float* x = (const float*)d_in[0];
    const int* ei = (const int*)d_in[1];
    const int* src = ei;
    const int* dst = ei + E;
    const float* Wl0 = (const float*)d_in[2];
    const float* bl0 = (const float*)d_in[3];
    const float* Wr0 = (const float*)d_in[4];
    const float* Wl1 = (const float*)d_in[5];
    const float* bl1 = (const float*)d_in[6];
    const float* Wr1 = (const float*)d_in[7];
    const float* Wl2 = (const float*)d_in[8];
    const float* bl2 = (const float*)d_in[9];
    const float* Wr2 = (const float*)d_in[10];
    float* out = (float*)d_out;

    // workspace carve-up  (N+1 rows for activation buffers: row N = zero sentinel)
    char* w = (char*)d_ws;
    int* deg = (int*)w;                 w += align_up((size_t)N * 4, 256);
    int* row_start = (int*)w;           w += align_up((size_t)N * 4, 256);
    int* gcntp = (int*)w;               w += align_up((size_t)MAXBUCK * GPAD * 4, 256);
    unsigned* recs = (unsigned*)w;      w += align_up((size_t)NBUCK * CAPB * 4, 256);
    int* srcs = (int*)w;                w += align_up((size_t)NBUCK * CAPB * 4, 256);
    unsigned short* xbf = (unsigned short*)w;   w += align_up((size_t)(N + 1) * 128 * 2, 256);
    unsigned short* hA = (unsigned short*)w;    w += align_up((size_t)(N + 1) * 128 * 2, 256);
    unsigned short* hB = (unsigned short*)w;    w += align_up((size_t)(N + 1) * 128 * 2, 256);
    unsigned short* meanb = (unsigned short*)w; w += align_up((size_t)N * 128 * 2, 256);
    unsigned short* Bp0 = (unsigned short*)w;   w += align_up(8 * 8 * 64 * 8 * 2, 256);
    unsigned short* Bp1 = (unsigned short*)w;   w += align_up(8 * 8 * 64 * 8 * 2, 256);
    unsigned short* Bp2 = (unsigned short*)w;   w += align_up(4 * 8 * 64 * 8 * 2, 256);
    float* bias2 = (float*)w;                   w += align_up(128 * 4, 256);
    unsigned short* z2 = xbf;       // alias: xbf dead after layer-0 gemm
    unsigned short* meanz = meanb;  // alias: meanb dead after layer-1 gemm

    // ---- CSR build (2-level binning) + conversions/packs ----
    hipMemsetAsync(gcntp, 0, (size_t)MAXBUCK * GPAD * 4, stream);
    partition_edges<<<(E + P1_EDGES - 1) / P1_EDGES, 256, 0, stream>>>(src, dst, E, NBUCK,
                                                                       recs, gcntp);
    to_bf16<<<((N + 1) * 32 + 255) / 256, 256, 0, stream>>>(x, xbf, N * 32, (N + 1) * 32);
    pack_w<128><<<(8 * 8 * 64 + 255) / 256, 256, 0, stream>>>(Wl0, Wr0, Bp0);
    pack_w<128><<<(8 * 8 * 64 + 255) / 256, 256, 0, stream>>>(Wl1, Wr1, Bp1);
    pack_w2<<<(4 * 8 * 64 + 255) / 256, 256, 0, stream>>>(Wl2, Wr2, Bp2);
    hipMemsetAsync(hA + (size_t)N * 128, 0, 256, stream);  // sentinel rows
    hipMemsetAsync(hB + (size_t)N * 128, 0, 256, stream);
    hipMemsetAsync(bias2, 0, 64 * 4, stream);
    hipMemcpyAsync(bias2 + 64, bl2, 64 * 4, hipMemcpyDeviceToDevice, stream);
    build_local_csr<<<NBUCK * 2, 256, 0, stream>>>(recs, gcntp, N, deg, row_start, srcs);

    const int aggGrid = (N + 15) / 16;     // 16 waves/block, 1 node/wave
    const int gemmGrid = (N + 127) / 128;  // 128 rows/block

    // ---- layer 0: x -> hA (relu+norm, bf16) ----
    aggregate128<<<aggGrid, 1024, 0, stream>>>(xbf, row_start, deg, srcs, meanb, N);
    sage_gemm<8, 128, 1, 1, 1><<<gemmGrid, 256, 0, stream>>>(meanb, xbf, Bp0, bl0, hA, N);

    // ---- layer 1: hA -> hB (relu+norm, bf16) ----
    aggregate128<<<aggGrid, 1024, 0, stream>>>(hA, row_start, deg, srcs, meanb, N);
    sage_gemm<8, 128, 1, 1, 1><<<gemmGrid, 256, 0, stream>>>(meanb, hA, Bp1, bl1, hB, N);

    // ---- layer 2 (commuted): z2 = [hB@Wl2 | hB@Wr2 + bl2], agg left, norm ----
    sage_gemm<4, 128, 0, 0, 1><<<gemmGrid, 256, 0, stream>>>(hB, hB, Bp2, bias2, z2, N);
    hipMemsetAsync(z2 + (size_t)N * 128, 0, 256, stream);  // sentinel row of z2
    aggregate64<<<aggGrid, 1024, 0, stream>>>(z2, row_start, deg, srcs, meanz, N);
    l2_epilogue<<<aggGrid, 1024, 0, stream>>>(meanz, z2, out, N);
}

// Round 7
// 426.310 us; speedup vs baseline: 1.6691x; 1.0203x over previous
//
#include <hip/hip_runtime.h>
#include <math.h>

// ---------------------------------------------------------------------------
// GraphSAGE 3-layer forward (v5): fp8 gather path.
//   - activations gathered as fp8-e4m3 with FIXED scales (x: 64, hA: 256 --
//     hA rows are L2-normalized so |elem|<=1), halving gather bytes, cache
//     lines, and VALU unpack work vs bf16.
//   - fp8 rows stored PERMUTED (byte p = m*8+nt, ch = (p&7)*16 + (p>>3)) so
//     the GEMM epilogue emits them with contiguous uint2 stores; the
//     aggregate un-permutes when writing the bf16 mean.
//   - dispatch count 25 -> 11 (prep_x, pack_all fusions; layer-2 epilogue
//     fused into agg64_norm -- no meanz round trip).
// ---------------------------------------------------------------------------

typedef __attribute__((ext_vector_type(8))) short short8;
typedef __attribute__((ext_vector_type(4))) float f32x4;
typedef __attribute__((ext_vector_type(2))) float f32x2;

#define BSHIFT 9
#define BSIZE 512
#define MAXBUCK 224
#define P1_EDGES 8192
#define P1_CAP 64
#define CAPB 10240
#define CAPH 5888
#define GPAD 16

#define XSCALE 64.0f    // x ~ N(0,1); clamp to +-440/64
#define HSCALE 256.0f   // hA rows unit-norm -> |elem|<=1 -> q<=256<448

__device__ __forceinline__ unsigned f2bf_rtn(float f) {
    unsigned u = __float_as_uint(f);
    return (u + 0x7fffu + ((u >> 16) & 1u)) >> 16;
}
__device__ __forceinline__ float bf_lo(unsigned v) { return __uint_as_float(v << 16); }
__device__ __forceinline__ float bf_hi(unsigned v) { return __uint_as_float(v & 0xffff0000u); }

// ---------------- pass 1: bin edges into bucket regions ----------------

__global__ __launch_bounds__(256) void partition_edges(const int* __restrict__ src,
                                                       const int* __restrict__ dst, int E,
                                                       int NBUCK,
                                                       unsigned* __restrict__ recs,
                                                       int* __restrict__ gcntp) {
    __shared__ int cnt[MAXBUCK];
    __shared__ int basem[MAXBUCK];
    __shared__ unsigned rec[MAXBUCK * P1_CAP];
    const int tid = threadIdx.x;
    for (int i = tid; i < NBUCK; i += 256) cnt[i] = 0;
    __syncthreads();

    const int base = blockIdx.x * P1_EDGES;
#pragma unroll
    for (int r = 0; r < P1_EDGES / 1024; r++) {
        int e = base + r * 1024 + tid * 4;
        if (e + 3 < E) {
            int4 s4 = *(const int4*)(src + e);
            int4 d4 = *(const int4*)(dst + e);
            int ss[4] = {s4.x, s4.y, s4.z, s4.w};
            int dd[4] = {d4.x, d4.y, d4.z, d4.w};
#pragma unroll
            for (int j = 0; j < 4; j++) {
                int b = dd[j] >> BSHIFT;
                unsigned rr = ((unsigned)ss[j] << BSHIFT) | (unsigned)(dd[j] & (BSIZE - 1));
                int pos = atomicAdd(&cnt[b], 1);
                if (pos < P1_CAP) {
                    rec[(b << 6) + pos] = rr;
                } else {
                    int gp = atomicAdd(&gcntp[b * GPAD], 1);
                    if (gp < CAPB) recs[(size_t)b * CAPB + gp] = rr;
                }
            }
        } else {
            for (int j = 0; j < 4; j++) {
                int ee = e + j;
                if (ee < E) {
                    int s = src[ee], d = dst[ee];
                    int b = d >> BSHIFT;
                    unsigned rr = ((unsigned)s << BSHIFT) | (unsigned)(d & (BSIZE - 1));
                    int pos = atomicAdd(&cnt[b], 1);
                    if (pos < P1_CAP) {
                        rec[(b << 6) + pos] = rr;
                    } else {
                        int gp = atomicAdd(&gcntp[b * GPAD], 1);
                        if (gp < CAPB) recs[(size_t)b * CAPB + gp] = rr;
                    }
                }
            }
        }
    }
    __syncthreads();

    for (int b = tid; b < NBUCK; b += 256) {
        int c = min(cnt[b], P1_CAP);
        cnt[b] = c;
        basem[b] = (c > 0) ? atomicAdd(&gcntp[b * GPAD], c) : 0;
    }
    __syncthreads();

    const int quads = NBUCK << 4;
    for (int sq = tid; sq < quads; sq += 256) {
        int b = sq >> 4, i0 = (sq & 15) << 2;
        int c = cnt[b];
        if (i0 < c) {
            int gp = basem[b] + i0;
            if (i0 + 3 < c && gp + 3 < CAPB) {
                uint4 v = *(const uint4*)&rec[(b << 6) + i0];
                *(uint4*)&recs[(size_t)b * CAPB + gp] = v;
            } else {
                for (int j = 0; j < 4 && i0 + j < c; j++) {
                    if (gp + j < CAPB) recs[(size_t)b * CAPB + gp + j] = rec[(b << 6) + i0 + j];
                }
            }
        }
    }
}

// ---------------- pass 2: per half-bucket local CSR (padded lists) ----------

__global__ __launch_bounds__(256) void build_local_csr(const unsigned* __restrict__ recs,
                                                       const int* __restrict__ gcntp, int N,
                                                       int* __restrict__ deg,
                                                       int* __restrict__ row_start,
                                                       int* __restrict__ srcs) {
    __shared__ int hist[512];
    __shared__ int excl[512];
    __shared__ int cur[512];
    __shared__ int tscan[256];
    __shared__ int htot0;
    __shared__ int stage[CAPH];

    const int tid = threadIdx.x;
    const int b = blockIdx.x >> 1;
    const int half = blockIdx.x & 1;
    const unsigned* r = recs + (size_t)b * CAPB;
    const int cnt = min(gcntp[b * GPAD], CAPB);

    hist[tid] = 0;
    hist[tid + 256] = 0;
    __syncthreads();
    for (int i = tid; i < cnt; i += 256) atomicAdd(&hist[r[i] & (BSIZE - 1)], 1);
    __syncthreads();

    for (int hs = 0; hs < 2; hs++) {
        int v = (hist[hs * 256 + tid] + 3) & ~3;
        tscan[tid] = v;
        __syncthreads();
        for (int off = 1; off < 256; off <<= 1) {
            int t = (tid >= off) ? tscan[tid - off] : 0;
            __syncthreads();
            tscan[tid] += t;
            __syncthreads();
        }
        int ex = tscan[tid] - v + (hs ? htot0 : 0);
        excl[hs * 256 + tid] = ex;
        cur[hs * 256 + tid] = ex;
        if (hs == 0 && tid == 255) htot0 = tscan[255];
        __syncthreads();
    }

    const int lbase = excl[half * 256];

    for (int i = tid; i < cnt; i += 256) {
        unsigned rr = r[i];
        int d = rr & (BSIZE - 1);
        if ((d >> 8) == half) {
            int pos = atomicAdd(&cur[d], 1) - lbase;
            if (pos < CAPH) stage[pos] = (int)(rr >> BSHIFT);
        }
    }
    __syncthreads();

    {
        int j = half * 256 + tid;
        int h0 = hist[j];
        int p = (h0 + 3) & ~3;
        int ex = excl[j] - lbase;
        for (int k = h0; k < p; k++)
            if (ex + k < CAPH) stage[ex + k] = N;
    }
    __syncthreads();

    const int last = half * 256 + 255;
    int mycnt = excl[last] + ((hist[last] + 3) & ~3) - lbase;
    mycnt = min(mycnt, CAPH);
    int* sb = srcs + (size_t)b * CAPB + lbase;
    for (int i = tid; i < mycnt; i += 256) sb[i] = stage[i];
    const int node = (b << BSHIFT) + half * 256 + tid;
    if (node < N) {
        deg[node] = hist[half * 256 + tid];
        row_start[node] = b * CAPB + excl[half * 256 + tid];
    }
}

// ---------------- prep: x -> bf16 row + permuted fp8 row (+sentinel) -------
// one wave per row; lane l holds channels 2l, 2l+1.

__global__ __launch_bounds__(256) void prep_x(const float* __restrict__ x,
                                              unsigned short* __restrict__ xbf,
                                              unsigned char* __restrict__ xq, int N) {
    int row = blockIdx.x * 4 + (threadIdx.x >> 6);
    if (row > N) return;
    int l = threadIdx.x & 63;
    float2 v = {0.f, 0.f};
    if (row < N) v = ((const float2*)x)[(size_t)row * 64 + l];

    ((unsigned*)xbf)[(size_t)row * 64 + l] = f2bf_rtn(v.x) | (f2bf_rtn(v.y) << 16);

    // transpose to permuted fp8 layout: lane m writes bytes p=8m..8m+7,
    // byte 8m+nt = fp8( x[ch=16nt+m] * XSCALE ). ch lives in lane (8nt+(m>>1)).
    float vv[8];
#pragma unroll
    for (int nt = 0; nt < 8; nt++) {
        int sl = 8 * nt + (l >> 1);
        float a = __shfl(v.x, sl, 64);
        float b = __shfl(v.y, sl, 64);
        float val = ((l & 1) ? b : a) * XSCALE;
        vv[nt] = fminf(fmaxf(val, -440.0f), 440.0f);
    }
    if (l < 16) {
        unsigned w0 = 0, w1 = 0;
        w0 = __builtin_amdgcn_cvt_pk_fp8_f32(vv[0], vv[1], w0, false);
        w0 = __builtin_amdgcn_cvt_pk_fp8_f32(vv[2], vv[3], w0, true);
        w1 = __builtin_amdgcn_cvt_pk_fp8_f32(vv[4], vv[5], w1, false);
        w1 = __builtin_amdgcn_cvt_pk_fp8_f32(vv[6], vv[7], w1, true);
        uint2 wq;
        wq.x = w0;
        wq.y = w1;
        ((uint2*)xq)[(size_t)row * 16 + l] = wq;
    }
}

// ---------------- pack_all: weight frags + bias2 + hAq sentinel -------------

__device__ __forceinline__ void pack_frag128(const float* Wl, const float* Wr,
                                             unsigned short* Bp, int idx) {
    int lane = idx & 63;
    int nt = (idx >> 6) % 8;
    int ks = (idx >> 6) / 8;
    int n = nt * 16 + (lane & 15);
    int k0 = ks * 32 + (lane >> 4) * 8;
#pragma unroll
    for (int j = 0; j < 8; j++) {
        int k = k0 + j;
        float w = (k < 128) ? Wl[k * 128 + n] : Wr[(k - 128) * 128 + n];
        Bp[(size_t)idx * 8 + j] = (unsigned short)f2bf_rtn(w);
    }
}

__device__ __forceinline__ void pack_frag2(const float* Wl, const float* Wr,
                                           unsigned short* Bp, int idx) {
    int lane = idx & 63;
    int nt = (idx >> 6) % 8;
    int ks = (idx >> 6) / 8;
    int n = nt * 16 + (lane & 15);
    int k0 = ks * 32 + (lane >> 4) * 8;
#pragma unroll
    for (int j = 0; j < 8; j++) {
        int k = k0 + j;
        float w = (n < 64) ? Wl[k * 64 + n] : Wr[k * 64 + (n - 64)];
        Bp[(size_t)idx * 8 + j] = (unsigned short)f2bf_rtn(w);
    }
}

__global__ __launch_bounds__(256) void pack_all(const float* __restrict__ Wl0,
                                                const float* __restrict__ Wr0,
                                                const float* __restrict__ Wl1,
                                                const float* __restrict__ Wr1,
                                                const float* __restrict__ Wl2,
                                                const float* __restrict__ Wr2,
                                                const float* __restrict__ bl2,
                                                unsigned short* __restrict__ Bp0,
                                                unsigned short* __restrict__ Bp1,
                                                unsigned short* __restrict__ Bp2,
                                                float* __restrict__ bias2,
                                                unsigned char* __restrict__ hAq, int N) {
    const int b = blockIdx.x, tid = threadIdx.x;
    if (b < 16) {
        pack_frag128(Wl0, Wr0, Bp0, b * 256 + tid);
    } else if (b < 32) {
        pack_frag128(Wl1, Wr1, Bp1, (b - 16) * 256 + tid);
    } else if (b < 40) {
        pack_frag2(Wl2, Wr2, Bp2, (b - 32) * 256 + tid);
    } else {
        if (tid < 64) {
            bias2[tid] = 0.0f;
            bias2[64 + tid] = bl2[tid];
        } else if (tid < 96) {
            ((unsigned*)(hAq + (size_t)N * 128))[tid - 64] = 0;  // fp8 sentinel row
        }
    }
}

// ---------------- aggregate: fp8 gather -> bf16 mean ------------------------
// 8 rows per dwordx4 instruction: g=lane>>3 row-group, c=lane&7 16B chunk.

__global__ __launch_bounds__(1024) void aggregate_fp8(const unsigned char* __restrict__ hq,
                                                      const int* __restrict__ row_start,
                                                      const int* __restrict__ deg,
                                                      const int* __restrict__ srcs,
                                                      unsigned short* __restrict__ mean,
                                                      int N, float unscale) {
    int node = blockIdx.x * 16 + (threadIdx.x >> 6);
    if (node >= N) return;
    int lane = threadIdx.x & 63;
    int g = lane >> 3, c = lane & 7;
    int start = row_start[node];
    int cnt = deg[node];
    int pcnt = (cnt + 3) & ~3;
    const uint4* hp = (const uint4*)hq;  // 8 uint4 per 128B fp8 row
    float a[16];
#pragma unroll
    for (int i = 0; i < 16; i++) a[i] = 0.0f;

    for (int e = 0; e < pcnt; e += 8) {
        int ee = e + g;
        int s0 = (ee < pcnt) ? srcs[start + ee] : N;  // sentinel zero row
        uint4 v = hp[(size_t)s0 * 8 + c];
        f32x2 p;
        p = __builtin_amdgcn_cvt_pk_f32_fp8(v.x, false); a[0] += p.x; a[1] += p.y;
        p = __builtin_amdgcn_cvt_pk_f32_fp8(v.x, true);  a[2] += p.x; a[3] += p.y;
        p = __builtin_amdgcn_cvt_pk_f32_fp8(v.y, false); a[4] += p.x; a[5] += p.y;
        p = __builtin_amdgcn_cvt_pk_f32_fp8(v.y, true);  a[6] += p.x; a[7] += p.y;
        p = __builtin_amdgcn_cvt_pk_f32_fp8(v.z, false); a[8] += p.x; a[9] += p.y;
        p = __builtin_amdgcn_cvt_pk_f32_fp8(v.z, true);  a[10] += p.x; a[11] += p.y;
        p = __builtin_amdgcn_cvt_pk_f32_fp8(v.w, false); a[12] += p.x; a[13] += p.y;
        p = __builtin_amdgcn_cvt_pk_f32_fp8(v.w, true);  a[14] += p.x; a[15] += p.y;
    }
#pragma unroll
    for (int i = 0; i < 16; i++) {
        a[i] += __shfl_xor(a[i], 8, 64);
        a[i] += __shfl_xor(a[i], 16, 64);
        a[i] += __shfl_xor(a[i], 32, 64);
    }
    if (g == 0) {
        float inv = unscale / fmaxf((float)cnt, 1.0f);
        // a[i] (i<8): ch=16i+2c ; a[i+8]: ch=16i+2c+1 -> dword idx 8i+c
#pragma unroll
        for (int nt = 0; nt < 8; nt++) {
            unsigned o = f2bf_rtn(a[nt] * inv) | (f2bf_rtn(a[nt + 8] * inv) << 16);
            ((unsigned*)mean)[(size_t)node * 64 + nt * 8 + c] = o;
        }
    }
}

// ---------------- layer-2: aggregate left half of z2 + fused norm -----------

__global__ __launch_bounds__(1024) void agg64_norm(const unsigned short* __restrict__ z2,
                                                   const int* __restrict__ row_start,
                                                   const int* __restrict__ deg,
                                                   const int* __restrict__ srcs,
                                                   float* __restrict__ out, int N) {
    int node = blockIdx.x * 16 + (threadIdx.x >> 6);
    if (node >= N) return;
    int lane = threadIdx.x & 63;
    int g = lane >> 3, c = lane & 7;
    int start = row_start[node];
    int cnt = deg[node];
    int pcnt = (cnt + 3) & ~3;
    const uint4* hp = (const uint4*)z2;  // 16 uint4 per 256B row; left = first 8
    float a[8] = {0.f, 0.f, 0.f, 0.f, 0.f, 0.f, 0.f, 0.f};

    for (int e = 0; e < pcnt; e += 8) {
        int ee = e + g;
        int s0 = (ee < pcnt) ? srcs[start + ee] : N;
        uint4 v = hp[(size_t)s0 * 16 + c];
        a[0] += bf_lo(v.x); a[1] += bf_hi(v.x);
        a[2] += bf_lo(v.y); a[3] += bf_hi(v.y);
        a[4] += bf_lo(v.z); a[5] += bf_hi(v.z);
        a[6] += bf_lo(v.w); a[7] += bf_hi(v.w);
    }
#pragma unroll
    for (int i = 0; i < 8; i++) {
        a[i] += __shfl_xor(a[i], 8, 64);
        a[i] += __shfl_xor(a[i], 16, 64);
        a[i] += __shfl_xor(a[i], 32, 64);
    }
    if (g == 0) {
        float inv = 1.0f / fmaxf((float)cnt, 1.0f);
        uint4 r = hp[(size_t)node * 16 + 8 + c];  // root: right half, ch 64+8c..
        float vv[8];
        vv[0] = a[0] * inv + bf_lo(r.x); vv[1] = a[1] * inv + bf_hi(r.x);
        vv[2] = a[2] * inv + bf_lo(r.y); vv[3] = a[3] * inv + bf_hi(r.y);
        vv[4] = a[4] * inv + bf_lo(r.z); vv[5] = a[5] * inv + bf_hi(r.z);
        vv[6] = a[6] * inv + bf_lo(r.w); vv[7] = a[7] * inv + bf_hi(r.w);
        float ss = 0.f;
#pragma unroll
        for (int i = 0; i < 8; i++) ss += vv[i] * vv[i];
        ss += __shfl_xor(ss, 1, 64);
        ss += __shfl_xor(ss, 2, 64);
        ss += __shfl_xor(ss, 4, 64);
        float rinv = 1.0f / fmaxf(sqrtf(ss), 1e-12f);
        float4 o0 = {vv[0] * rinv, vv[1] * rinv, vv[2] * rinv, vv[3] * rinv};
        float4 o1 = {vv[4] * rinv, vv[5] * rinv, vv[6] * rinv, vv[7] * rinv};
        ((float4*)out)[(size_t)node * 16 + 2 * c] = o0;
        ((float4*)out)[(size_t)node * 16 + 2 * c + 1] = o1;
    }
}

// ---------------- MFMA GEMM + bias (+norm/relu, + optional fp8 emit) --------

template <int KT, int DOUT, int RELU, int NORM, int BF16OUT, int EMITFP8>
__global__ __launch_bounds__(256) void sage_gemm(const unsigned short* __restrict__ meanb,
                                                 const unsigned short* __restrict__ hb,
                                                 const unsigned short* __restrict__ Bp,
                                                 const float* __restrict__ bias,
                                                 void* __restrict__ outp,
                                                 unsigned char* __restrict__ hq, int N) {
    constexpr int NT = DOUT / 16;
    constexpr int MT = 2;
    __shared__ short Bl[KT * NT * 64 * 8];

    const int tid = threadIdx.x;
    {
        const uint4* s = (const uint4*)Bp;
        uint4* d = (uint4*)Bl;
        constexpr int CNT = KT * NT * 64;
        for (int i = tid; i < CNT; i += 256) d[i] = s[i];
    }
    __syncthreads();

    const int wave = tid >> 6;
    const int lane = tid & 63;
    const int m = lane & 15;
    const int q = lane >> 4;
    const int rowbase = blockIdx.x * (64 * MT);

    int rowA[MT];
#pragma unroll
    for (int t = 0; t < MT; t++) rowA[t] = rowbase + (wave * MT + t) * 16 + m;

    f32x4 acc[MT][NT];
#pragma unroll
    for (int t = 0; t < MT; t++)
#pragma unroll
        for (int nt = 0; nt < NT; nt++) acc[t][nt] = (f32x4)0.0f;

#pragma unroll
    for (int ks = 0; ks < KT; ks++) {
        const unsigned short* ab = (KT == 8) ? ((ks < 4) ? meanb : hb) : hb;
        const int koff = (KT == 8 ? (ks & 3) : ks) * 32 + q * 8;
        short8 afrag[MT];
#pragma unroll
        for (int t = 0; t < MT; t++) {
            if (rowA[t] < N)
                afrag[t] = *(const short8*)(ab + (size_t)rowA[t] * 128 + koff);
            else
                afrag[t] = (short8)(short)0;
        }
#pragma unroll
        for (int nt = 0; nt < NT; nt++) {
            short8 bfrag = *(const short8*)&Bl[((ks * NT + nt) * 64 + lane) * 8];
#pragma unroll
            for (int t = 0; t < MT; t++)
                acc[t][nt] = __builtin_amdgcn_mfma_f32_16x16x32_bf16(afrag[t], bfrag,
                                                                     acc[t][nt], 0, 0, 0);
        }
    }

    float bs[NT];
#pragma unroll
    for (int nt = 0; nt < NT; nt++) bs[nt] = bias[nt * 16 + m];

#pragma unroll
    for (int t = 0; t < MT; t++) {
        float rinv[4] = {1.f, 1.f, 1.f, 1.f};
#pragma unroll
        for (int nt = 0; nt < NT; nt++)
#pragma unroll
            for (int r = 0; r < 4; r++) acc[t][nt][r] += bs[nt];
        if (NORM) {
            float ss[4] = {0.f, 0.f, 0.f, 0.f};
#pragma unroll
            for (int nt = 0; nt < NT; nt++)
#pragma unroll
                for (int r = 0; r < 4; r++) ss[r] += acc[t][nt][r] * acc[t][nt][r];
#pragma unroll
            for (int msk = 1; msk < 16; msk <<= 1)
#pragma unroll
                for (int r = 0; r < 4; r++) ss[r] += __shfl_xor(ss[r], msk, 64);
#pragma unroll
            for (int r = 0; r < 4; r++) rinv[r] = 1.0f / fmaxf(sqrtf(ss[r]), 1e-12f);
        }

#pragma unroll
        for (int r = 0; r < 4; r++) {
            int row = rowbase + (wave * MT + t) * 16 + q * 4 + r;
            if (row < N) {
                float vv[NT];
#pragma unroll
                for (int nt = 0; nt < NT; nt++) {
                    float v = acc[t][nt][r];
                    if (NORM) v *= rinv[r];
                    if (RELU) v = fmaxf(v, 0.0f);
                    vv[nt] = v;
                    int col = nt * 16 + m;
                    if (BF16OUT)
                        ((unsigned short*)outp)[(size_t)row * DOUT + col] =
                            (unsigned short)f2bf_rtn(v);
                    else
                        ((float*)outp)[(size_t)row * DOUT + col] = v;
                }
                if constexpr (EMITFP8) {
                    // permuted fp8 row: lane m writes bytes 8m..8m+7 (nt order)
                    unsigned w0 = 0, w1 = 0;
                    w0 = __builtin_amdgcn_cvt_pk_fp8_f32(vv[0] * HSCALE, vv[1] * HSCALE, w0, false);
                    w0 = __builtin_amdgcn_cvt_pk_fp8_f32(vv[2] * HSCALE, vv[3] * HSCALE, w0, true);
                    w1 = __builtin_amdgcn_cvt_pk_fp8_f32(vv[4] * HSCALE, vv[5] * HSCALE, w1, false);
                    w1 = __builtin_amdgcn_cvt_pk_fp8_f32(vv[6] * HSCALE, vv[7] * HSCALE, w1, true);
                    uint2 wq;
                    wq.x = w0;
                    wq.y = w1;
                    ((uint2*)hq)[(size_t)row * 16 + m] = wq;
                }
            }
        }
    }
}

static inline size_t align_up(size_t x, size_t a) { return (x + a - 1) & ~(a - 1); }

extern "C" void kernel_launch(void* const* d_in, const int* in_sizes, int n_in,
                              void* d_out, int out_size, void* d_ws, size_t ws_size,
                              hipStream_t stream) {
    const int N = in_sizes[0] / 128;
    const int E = in_sizes[1] / 2;
    const int NBUCK = (N + BSIZE - 1) >> BSHIFT;

    const float* x = (const float*)d_in[0];
    const int* ei = (const int*)d_in[1];
    const int* src = ei;
    const int* dst = ei + E;
    const float* Wl0 = (const float*)d_in[2];
    const float* bl0 = (const float*)d_in[3];
    const float* Wr0 = (const float*)d_in[4];
    const float* Wl1 = (const float*)d_in[5];
    const float* bl1 = (const float*)d_in[6];
    const float* Wr1 = (const float*)d_in[7];
    const float* Wl2 = (const float*)d_in[8];
    const float* bl2 = (const float*)d_in[9];
    const float* Wr2 = (const float*)d_in[10];
    float* out = (float*)d_out;

    char* w = (char*)d_ws;
    int* deg = (int*)w;                 w += align_up((size_t)N * 4, 256);
    int* row_start = (int*)w;           w += align_up((size_t)N * 4, 256);
    int* gcntp = (int*)w;               w += align_up((size_t)MAXBUCK * GPAD * 4, 256);
    unsigned* recs = (unsigned*)w;      w += align_up((size_t)NBUCK * CAPB * 4, 256);
    int* srcs = (int*)w;                w += align_up((size_t)NBUCK * CAPB * 4, 256);
    unsigned short* xbf = (unsigned short*)w;  w += align_up((size_t)(N + 1) * 128 * 2, 256);
    unsigned char* xq = (unsigned char*)w;     w += align_up((size_t)(N + 1) * 128, 256);
    unsigned char* hAq = (unsigned char*)w;    w += align_up((size_t)(N + 1) * 128, 256);
    unsigned short* hA = (unsigned short*)w;   w += align_up((size_t)N * 128 * 2, 256);
    unsigned short* hB = (unsigned short*)w;   w += align_up((size_t)N * 128 * 2, 256);
    unsigned short* meanb = (unsigned short*)w; w += align_up((size_t)N * 128 * 2, 256);
    unsigned short* Bp0 = (unsigned short*)w;  w += align_up(8 * 8 * 64 * 8 * 2, 256);
    unsigned short* Bp1 = (unsigned short*)w;  w += align_up(8 * 8 * 64 * 8 * 2, 256);
    unsigned short* Bp2 = (unsigned short*)w;  w += align_up(4 * 8 * 64 * 8 * 2, 256);
    float* bias2 = (float*)w;                  w += align_up(128 * 4, 256);
    unsigned short* z2 = xbf;  // alias: xbf dead after layer-0 gemm; row N stays 0

    hipMemsetAsync(gcntp, 0, (size_t)MAXBUCK * GPAD * 4, stream);
    partition_edges<<<(E + P1_EDGES - 1) / P1_EDGES, 256, 0, stream>>>(src, dst, E, NBUCK,
                                                                       recs, gcntp);
    prep_x<<<(N + 4) / 4, 256, 0, stream>>>(x, xbf, xq, N);
    pack_all<<<41, 256, 0, stream>>>(Wl0, Wr0, Wl1, Wr1, Wl2, Wr2, bl2, Bp0, Bp1, Bp2,
                                     bias2, hAq, N);
    build_local_csr<<<NBUCK * 2, 256, 0, stream>>>(recs, gcntp, N, deg, row_start, srcs);

    const int aggGrid = (N + 15) / 16;
    const int gemmGrid = (N + 127) / 128;

    // ---- layer 0: agg(x_fp8) -> gemm -> hA bf16 + hAq fp8 ----
    aggregate_fp8<<<aggGrid, 1024, 0, stream>>>(xq, row_start, deg, srcs, meanb, N,
                                                1.0f / XSCALE);
    sage_gemm<8, 128, 1, 1, 1, 1><<<gemmGrid, 256, 0, stream>>>(meanb, xbf, Bp0, bl0, hA,
                                                                hAq, N);

    // ---- layer 1: agg(hAq) -> gemm -> hB bf16 ----
    aggregate_fp8<<<aggGrid, 1024, 0, stream>>>(hAq, row_start, deg, srcs, meanb, N,
                                                1.0f / HSCALE);
    sage_gemm<8, 128, 1, 1, 1, 0><<<gemmGrid, 256, 0, stream>>>(meanb, hA, Bp1, bl1, hB,
                                                                nullptr, N);

    // ---- layer 2 (commuted): z2 = [hB@Wl2 | hB@Wr2+bl2]; agg left + norm ----
    sage_gemm<4, 128, 0, 0, 1, 0><<<gemmGrid, 256, 0, stream>>>(hB, hB, Bp2, bias2, z2,
                                                                nullptr, N);
    agg64_norm<<<aggGrid, 1024, 0, stream>>>(z2, row_start, deg, srcs, out, N);
}

// Round 8
// 402.144 us; speedup vs baseline: 1.7694x; 1.0601x over previous
//
#include <hip/hip_runtime.h>
#include <math.h>

// ---------------------------------------------------------------------------
// GraphSAGE 3-layer forward (v6): fp8 gather, short-row-optimized aggregate.
//   - aggregate_fp8: uint2/lane (16 lanes cover one 128B fp8 row), 4 row
//     groups, 2 independent gathers per iteration, 8 accumulators, 24 shfls
//     (was 48), single int2 {row_start,deg} prologue load.
//   - CSR stores rsdeg packed int2.
//   - prep_x + pack_all merged into one dispatch (10 total).
// ---------------------------------------------------------------------------

typedef __attribute__((ext_vector_type(8))) short short8;
typedef __attribute__((ext_vector_type(4))) float f32x4;
typedef __attribute__((ext_vector_type(2))) float f32x2;

#define BSHIFT 9
#define BSIZE 512
#define MAXBUCK 224
#define P1_EDGES 8192
#define P1_CAP 64
#define CAPB 10240
#define CAPH 5888
#define GPAD 16

#define XSCALE 64.0f    // x ~ N(0,1); clamp to +-440/64
#define HSCALE 256.0f   // hA rows unit-norm -> |elem|<=1 -> q<=256<448

__device__ __forceinline__ unsigned f2bf_rtn(float f) {
    unsigned u = __float_as_uint(f);
    return (u + 0x7fffu + ((u >> 16) & 1u)) >> 16;
}
__device__ __forceinline__ float bf_lo(unsigned v) { return __uint_as_float(v << 16); }
__device__ __forceinline__ float bf_hi(unsigned v) { return __uint_as_float(v & 0xffff0000u); }

// ---------------- pass 1: bin edges into bucket regions ----------------

__global__ __launch_bounds__(256) void partition_edges(const int* __restrict__ src,
                                                       const int* __restrict__ dst, int E,
                                                       int NBUCK,
                                                       unsigned* __restrict__ recs,
                                                       int* __restrict__ gcntp) {
    __shared__ int cnt[MAXBUCK];
    __shared__ int basem[MAXBUCK];
    __shared__ unsigned rec[MAXBUCK * P1_CAP];
    const int tid = threadIdx.x;
    for (int i = tid; i < NBUCK; i += 256) cnt[i] = 0;
    __syncthreads();

    const int base = blockIdx.x * P1_EDGES;
#pragma unroll
    for (int r = 0; r < P1_EDGES / 1024; r++) {
        int e = base + r * 1024 + tid * 4;
        if (e + 3 < E) {
            int4 s4 = *(const int4*)(src + e);
            int4 d4 = *(const int4*)(dst + e);
            int ss[4] = {s4.x, s4.y, s4.z, s4.w};
            int dd[4] = {d4.x, d4.y, d4.z, d4.w};
#pragma unroll
            for (int j = 0; j < 4; j++) {
                int b = dd[j] >> BSHIFT;
                unsigned rr = ((unsigned)ss[j] << BSHIFT) | (unsigned)(dd[j] & (BSIZE - 1));
                int pos = atomicAdd(&cnt[b], 1);
                if (pos < P1_CAP) {
                    rec[(b << 6) + pos] = rr;
                } else {
                    int gp = atomicAdd(&gcntp[b * GPAD], 1);
                    if (gp < CAPB) recs[(size_t)b * CAPB + gp] = rr;
                }
            }
        } else {
            for (int j = 0; j < 4; j++) {
                int ee = e + j;
                if (ee < E) {
                    int s = src[ee], d = dst[ee];
                    int b = d >> BSHIFT;
                    unsigned rr = ((unsigned)s << BSHIFT) | (unsigned)(d & (BSIZE - 1));
                    int pos = atomicAdd(&cnt[b], 1);
                    if (pos < P1_CAP) {
                        rec[(b << 6) + pos] = rr;
                    } else {
                        int gp = atomicAdd(&gcntp[b * GPAD], 1);
                        if (gp < CAPB) recs[(size_t)b * CAPB + gp] = rr;
                    }
                }
            }
        }
    }
    __syncthreads();

    for (int b = tid; b < NBUCK; b += 256) {
        int c = min(cnt[b], P1_CAP);
        cnt[b] = c;
        basem[b] = (c > 0) ? atomicAdd(&gcntp[b * GPAD], c) : 0;
    }
    __syncthreads();

    const int quads = NBUCK << 4;
    for (int sq = tid; sq < quads; sq += 256) {
        int b = sq >> 4, i0 = (sq & 15) << 2;
        int c = cnt[b];
        if (i0 < c) {
            int gp = basem[b] + i0;
            if (i0 + 3 < c && gp + 3 < CAPB) {
                uint4 v = *(const uint4*)&rec[(b << 6) + i0];
                *(uint4*)&recs[(size_t)b * CAPB + gp] = v;
            } else {
                for (int j = 0; j < 4 && i0 + j < c; j++) {
                    if (gp + j < CAPB) recs[(size_t)b * CAPB + gp + j] = rec[(b << 6) + i0 + j];
                }
            }
        }
    }
}

// ---------------- pass 2: per half-bucket local CSR (padded lists) ----------

__global__ __launch_bounds__(256) void build_local_csr(const unsigned* __restrict__ recs,
                                                       const int* __restrict__ gcntp, int N,
                                                       int2* __restrict__ rsdeg,
                                                       int* __restrict__ srcs) {
    __shared__ int hist[512];
    __shared__ int excl[512];
    __shared__ int cur[512];
    __shared__ int tscan[256];
    __shared__ int htot0;
    __shared__ int stage[CAPH];

    const int tid = threadIdx.x;
    const int b = blockIdx.x >> 1;
    const int half = blockIdx.x & 1;
    const unsigned* r = recs + (size_t)b * CAPB;
    const int cnt = min(gcntp[b * GPAD], CAPB);

    hist[tid] = 0;
    hist[tid + 256] = 0;
    __syncthreads();
    for (int i = tid; i < cnt; i += 256) atomicAdd(&hist[r[i] & (BSIZE - 1)], 1);
    __syncthreads();

    for (int hs = 0; hs < 2; hs++) {
        int v = (hist[hs * 256 + tid] + 3) & ~3;
        tscan[tid] = v;
        __syncthreads();
        for (int off = 1; off < 256; off <<= 1) {
            int t = (tid >= off) ? tscan[tid - off] : 0;
            __syncthreads();
            tscan[tid] += t;
            __syncthreads();
        }
        int ex = tscan[tid] - v + (hs ? htot0 : 0);
        excl[hs * 256 + tid] = ex;
        cur[hs * 256 + tid] = ex;
        if (hs == 0 && tid == 255) htot0 = tscan[255];
        __syncthreads();
    }

    const int lbase = excl[half * 256];

    for (int i = tid; i < cnt; i += 256) {
        unsigned rr = r[i];
        int d = rr & (BSIZE - 1);
        if ((d >> 8) == half) {
            int pos = atomicAdd(&cur[d], 1) - lbase;
            if (pos < CAPH) stage[pos] = (int)(rr >> BSHIFT);
        }
    }
    __syncthreads();

    {
        int j = half * 256 + tid;
        int h0 = hist[j];
        int p = (h0 + 3) & ~3;
        int ex = excl[j] - lbase;
        for (int k = h0; k < p; k++)
            if (ex + k < CAPH) stage[ex + k] = N;
    }
    __syncthreads();

    const int last = half * 256 + 255;
    int mycnt = excl[last] + ((hist[last] + 3) & ~3) - lbase;
    mycnt = min(mycnt, CAPH);
    int* sb = srcs + (size_t)b * CAPB + lbase;
    for (int i = tid; i < mycnt; i += 256) sb[i] = stage[i];
    const int node = (b << BSHIFT) + half * 256 + tid;
    if (node < N) {
        int2 rd;
        rd.x = b * CAPB + excl[half * 256 + tid];
        rd.y = hist[half * 256 + tid];
        rsdeg[node] = rd;
    }
}

// ---------------- prep_all: x conversion + weight packs (one dispatch) ------

__device__ __forceinline__ void pack_frag128(const float* Wl, const float* Wr,
                                             unsigned short* Bp, int idx) {
    int lane = idx & 63;
    int nt = (idx >> 6) % 8;
    int ks = (idx >> 6) / 8;
    int n = nt * 16 + (lane & 15);
    int k0 = ks * 32 + (lane >> 4) * 8;
#pragma unroll
    for (int j = 0; j < 8; j++) {
        int k = k0 + j;
        float w = (k < 128) ? Wl[k * 128 + n] : Wr[(k - 128) * 128 + n];
        Bp[(size_t)idx * 8 + j] = (unsigned short)f2bf_rtn(w);
    }
}

__device__ __forceinline__ void pack_frag2(const float* Wl, const float* Wr,
                                           unsigned short* Bp, int idx) {
    int lane = idx & 63;
    int nt = (idx >> 6) % 8;
    int ks = (idx >> 6) / 8;
    int n = nt * 16 + (lane & 15);
    int k0 = ks * 32 + (lane >> 4) * 8;
#pragma unroll
    for (int j = 0; j < 8; j++) {
        int k = k0 + j;
        float w = (n < 64) ? Wl[k * 64 + n] : Wr[k * 64 + (n - 64)];
        Bp[(size_t)idx * 8 + j] = (unsigned short)f2bf_rtn(w);
    }
}

__global__ __launch_bounds__(256) void prep_all(const float* __restrict__ x,
                                                unsigned short* __restrict__ xbf,
                                                unsigned char* __restrict__ xq,
                                                const float* __restrict__ Wl0,
                                                const float* __restrict__ Wr0,
                                                const float* __restrict__ Wl1,
                                                const float* __restrict__ Wr1,
                                                const float* __restrict__ Wl2,
                                                const float* __restrict__ Wr2,
                                                const float* __restrict__ bl2,
                                                unsigned short* __restrict__ Bp0,
                                                unsigned short* __restrict__ Bp1,
                                                unsigned short* __restrict__ Bp2,
                                                float* __restrict__ bias2,
                                                unsigned char* __restrict__ hAq, int N,
                                                int PB) {
    const int b = blockIdx.x, tid = threadIdx.x;
    if (b < PB) {
        // x rows -> bf16 + permuted fp8 (row N = zero sentinel)
        int row = b * 4 + (tid >> 6);
        if (row > N) return;
        int l = tid & 63;
        float2 v = {0.f, 0.f};
        if (row < N) v = ((const float2*)x)[(size_t)row * 64 + l];
        ((unsigned*)xbf)[(size_t)row * 64 + l] = f2bf_rtn(v.x) | (f2bf_rtn(v.y) << 16);
        float vv[8];
#pragma unroll
        for (int nt = 0; nt < 8; nt++) {
            int sl = 8 * nt + (l >> 1);
            float a = __shfl(v.x, sl, 64);
            float bb = __shfl(v.y, sl, 64);
            float val = ((l & 1) ? bb : a) * XSCALE;
            vv[nt] = fminf(fmaxf(val, -440.0f), 440.0f);
        }
        if (l < 16) {
            unsigned w0 = 0, w1 = 0;
            w0 = __builtin_amdgcn_cvt_pk_fp8_f32(vv[0], vv[1], w0, false);
            w0 = __builtin_amdgcn_cvt_pk_fp8_f32(vv[2], vv[3], w0, true);
            w1 = __builtin_amdgcn_cvt_pk_fp8_f32(vv[4], vv[5], w1, false);
            w1 = __builtin_amdgcn_cvt_pk_fp8_f32(vv[6], vv[7], w1, true);
            uint2 wq;
            wq.x = w0;
            wq.y = w1;
            ((uint2*)xq)[(size_t)row * 16 + l] = wq;
        }
        return;
    }
    const int pb = b - PB;
    if (pb < 16) {
        pack_frag128(Wl0, Wr0, Bp0, pb * 256 + tid);
    } else if (pb < 32) {
        pack_frag128(Wl1, Wr1, Bp1, (pb - 16) * 256 + tid);
    } else if (pb < 40) {
        pack_frag2(Wl2, Wr2, Bp2, (pb - 32) * 256 + tid);
    } else {
        if (tid < 64) {
            bias2[tid] = 0.0f;
            bias2[64 + tid] = bl2[tid];
        } else if (tid < 96) {
            ((unsigned*)(hAq + (size_t)N * 128))[tid - 64] = 0;  // fp8 sentinel row
        }
    }
}

// ---------------- aggregate: fp8 gather -> bf16 mean (short-row tuned) ------
// 16 lanes cover one 128B fp8 row (uint2/lane); g=lane>>4 row-group (4 rows
// per instruction), 2 independent gathers per iteration (8 edges).
// Permuted layout: byte 8m+nt of row = ch nt*16+m -> lane c accumulates
// a[j] = ch 16j+c.

__global__ __launch_bounds__(1024) void aggregate_fp8(const unsigned char* __restrict__ hq,
                                                      const int2* __restrict__ rsdeg,
                                                      const int* __restrict__ srcs,
                                                      unsigned short* __restrict__ mean,
                                                      int N, float unscale) {
    int node = blockIdx.x * 16 + (threadIdx.x >> 6);
    if (node >= N) return;
    int lane = threadIdx.x & 63;
    int g = lane >> 4, c = lane & 15;
    int2 rd = rsdeg[node];
    int start = rd.x, cnt = rd.y;
    int pcnt = (cnt + 3) & ~3;
    const uint2* hp = (const uint2*)hq;  // 16 uint2 per 128B fp8 row
    float a[8] = {0.f, 0.f, 0.f, 0.f, 0.f, 0.f, 0.f, 0.f};

    for (int e = 0; e < pcnt; e += 8) {
        int s0 = srcs[start + e + g];          // e+g < pcnt (x4 padding)
        int ee1 = e + 4 + g;
        int s1 = (ee1 < pcnt) ? srcs[start + ee1] : N;  // sentinel zero row
        uint2 v0 = hp[(size_t)s0 * 16 + c];
        uint2 v1 = hp[(size_t)s1 * 16 + c];
        f32x2 p;
        p = __builtin_amdgcn_cvt_pk_f32_fp8(v0.x, false); a[0] += p.x; a[1] += p.y;
        p = __builtin_amdgcn_cvt_pk_f32_fp8(v0.x, true);  a[2] += p.x; a[3] += p.y;
        p = __builtin_amdgcn_cvt_pk_f32_fp8(v0.y, false); a[4] += p.x; a[5] += p.y;
        p = __builtin_amdgcn_cvt_pk_f32_fp8(v0.y, true);  a[6] += p.x; a[7] += p.y;
        p = __builtin_amdgcn_cvt_pk_f32_fp8(v1.x, false); a[0] += p.x; a[1] += p.y;
        p = __builtin_amdgcn_cvt_pk_f32_fp8(v1.x, true);  a[2] += p.x; a[3] += p.y;
        p = __builtin_amdgcn_cvt_pk_f32_fp8(v1.y, false); a[4] += p.x; a[5] += p.y;
        p = __builtin_amdgcn_cvt_pk_f32_fp8(v1.y, true);  a[6] += p.x; a[7] += p.y;
    }
    // reduce over the 4 row groups
#pragma unroll
    for (int i = 0; i < 8; i++) {
        a[i] += __shfl_xor(a[i], 16, 64);
        a[i] += __shfl_xor(a[i], 32, 64);
    }
    // pair even/odd channels: lane c holds ch 16j+c; partner ch 16j+c+1
    float bpair[8];
#pragma unroll
    for (int i = 0; i < 8; i++) bpair[i] = __shfl_xor(a[i], 1, 64);
    if (g == 0 && (c & 1) == 0) {
        float inv = unscale / fmaxf((float)cnt, 1.0f);
#pragma unroll
        for (int j = 0; j < 8; j++) {
            unsigned o = f2bf_rtn(a[j] * inv) | (f2bf_rtn(bpair[j] * inv) << 16);
            ((unsigned*)mean)[(size_t)node * 64 + j * 8 + (c >> 1)] = o;
        }
    }
}

// ---------------- layer-2: aggregate left half of z2 + fused norm -----------

__global__ __launch_bounds__(1024) void agg64_norm(const unsigned short* __restrict__ z2,
                                                   const int2* __restrict__ rsdeg,
                                                   const int* __restrict__ srcs,
                                                   float* __restrict__ out, int N) {
    int node = blockIdx.x * 16 + (threadIdx.x >> 6);
    if (node >= N) return;
    int lane = threadIdx.x & 63;
    int g = lane >> 3, c = lane & 7;
    int2 rd = rsdeg[node];
    int start = rd.x, cnt = rd.y;
    int pcnt = (cnt + 3) & ~3;
    const uint4* hp = (const uint4*)z2;  // 16 uint4 per 256B row; left = first 8
    float a[8] = {0.f, 0.f, 0.f, 0.f, 0.f, 0.f, 0.f, 0.f};

    for (int e = 0; e < pcnt; e += 8) {
        int ee = e + g;
        int s0 = (ee < pcnt) ? srcs[start + ee] : N;
        uint4 v = hp[(size_t)s0 * 16 + c];
        a[0] += bf_lo(v.x); a[1] += bf_hi(v.x);
        a[2] += bf_lo(v.y); a[3] += bf_hi(v.y);
        a[4] += bf_lo(v.z); a[5] += bf_hi(v.z);
        a[6] += bf_lo(v.w); a[7] += bf_hi(v.w);
    }
#pragma unroll
    for (int i = 0; i < 8; i++) {
        a[i] += __shfl_xor(a[i], 8, 64);
        a[i] += __shfl_xor(a[i], 16, 64);
        a[i] += __shfl_xor(a[i], 32, 64);
    }
    if (g == 0) {
        float inv = 1.0f / fmaxf((float)cnt, 1.0f);
        uint4 r = hp[(size_t)node * 16 + 8 + c];
        float vv[8];
        vv[0] = a[0] * inv + bf_lo(r.x); vv[1] = a[1] * inv + bf_hi(r.x);
        vv[2] = a[2] * inv + bf_lo(r.y); vv[3] = a[3] * inv + bf_hi(r.y);
        vv[4] = a[4] * inv + bf_lo(r.z); vv[5] = a[5] * inv + bf_hi(r.z);
        vv[6] = a[6] * inv + bf_lo(r.w); vv[7] = a[7] * inv + bf_hi(r.w);
        float ss = 0.f;
#pragma unroll
        for (int i = 0; i < 8; i++) ss += vv[i] * vv[i];
        ss += __shfl_xor(ss, 1, 64);
        ss += __shfl_xor(ss, 2, 64);
        ss += __shfl_xor(ss, 4, 64);
        float rinv = 1.0f / fmaxf(sqrtf(ss), 1e-12f);
        float4 o0 = {vv[0] * rinv, vv[1] * rinv, vv[2] * rinv, vv[3] * rinv};
        float4 o1 = {vv[4] * rinv, vv[5] * rinv, vv[6] * rinv, vv[7] * rinv};
        ((float4*)out)[(size_t)node * 16 + 2 * c] = o0;
        ((float4*)out)[(size_t)node * 16 + 2 * c + 1] = o1;
    }
}

// ---------------- MFMA GEMM + bias (+norm/relu, + optional fp8 emit) --------

template <int KT, int DOUT, int RELU, int NORM, int BF16OUT, int EMITFP8>
__global__ __launch_bounds__(256) void sage_gemm(const unsigned short* __restrict__ meanb,
                                                 const unsigned short* __restrict__ hb,
                                                 const unsigned short* __restrict__ Bp,
                                                 const float* __restrict__ bias,
                                                 void* __restrict__ outp,
                                                 unsigned char* __restrict__ hq, int N) {
    constexpr int NT = DOUT / 16;
    constexpr int MT = 2;
    __shared__ short Bl[KT * NT * 64 * 8];

    const int tid = threadIdx.x;
    {
        const uint4* s = (const uint4*)Bp;
        uint4* d = (uint4*)Bl;
        constexpr int CNT = KT * NT * 64;
        for (int i = tid; i < CNT; i += 256) d[i] = s[i];
    }
    __syncthreads();

    const int wave = tid >> 6;
    const int lane = tid & 63;
    const int m = lane & 15;
    const int q = lane >> 4;
    const int rowbase = blockIdx.x * (64 * MT);

    int rowA[MT];
#pragma unroll
    for (int t = 0; t < MT; t++) rowA[t] = rowbase + (wave * MT + t) * 16 + m;

    f32x4 acc[MT][NT];
#pragma unroll
    for (int t = 0; t < MT; t++)
#pragma unroll
        for (int nt = 0; nt < NT; nt++) acc[t][nt] = (f32x4)0.0f;

#pragma unroll
    for (int ks = 0; ks < KT; ks++) {
        const unsigned short* ab = (KT == 8) ? ((ks < 4) ? meanb : hb) : hb;
        const int koff = (KT == 8 ? (ks & 3) : ks) * 32 + q * 8;
        short8 afrag[MT];
#pragma unroll
        for (int t = 0; t < MT; t++) {
            if (rowA[t] < N)
                afrag[t] = *(const short8*)(ab + (size_t)rowA[t] * 128 + koff);
            else
                afrag[t] = (short8)(short)0;
        }
#pragma unroll
        for (int nt = 0; nt < NT; nt++) {
            short8 bfrag = *(const short8*)&Bl[((ks * NT + nt) * 64 + lane) * 8];
#pragma unroll
            for (int t = 0; t < MT; t++)
                acc[t][nt] = __builtin_amdgcn_mfma_f32_16x16x32_bf16(afrag[t], bfrag,
                                                                     acc[t][nt], 0, 0, 0);
        }
    }

    float bs[NT];
#pragma unroll
    for (int nt = 0; nt < NT; nt++) bs[nt] = bias[nt * 16 + m];

#pragma unroll
    for (int t = 0; t < MT; t++) {
        float rinv[4] = {1.f, 1.f, 1.f, 1.f};
#pragma unroll
        for (int nt = 0; nt < NT; nt++)
#pragma unroll
            for (int r = 0; r < 4; r++) acc[t][nt][r] += bs[nt];
        if (NORM) {
            float ss[4] = {0.f, 0.f, 0.f, 0.f};
#pragma unroll
            for (int nt = 0; nt < NT; nt++)
#pragma unroll
                for (int r = 0; r < 4; r++) ss[r] += acc[t][nt][r] * acc[t][nt][r];
#pragma unroll
            for (int msk = 1; msk < 16; msk <<= 1)
#pragma unroll
                for (int r = 0; r < 4; r++) ss[r] += __shfl_xor(ss[r], msk, 64);
#pragma unroll
            for (int r = 0; r < 4; r++) rinv[r] = 1.0f / fmaxf(sqrtf(ss[r]), 1e-12f);
        }

#pragma unroll
        for (int r = 0; r < 4; r++) {
            int row = rowbase + (wave * MT + t) * 16 + q * 4 + r;
            if (row < N) {
                float vv[NT];
#pragma unroll
                for (int nt = 0; nt < NT; nt++) {
                    float v = acc[t][nt][r];
                    if (NORM) v *= rinv[r];
                    if (RELU) v = fmaxf(v, 0.0f);
                    vv[nt] = v;
                    int col = nt * 16 + m;
                    if (BF16OUT)
                        ((unsigned short*)outp)[(size_t)row * DOUT + col] =
                            (unsigned short)f2bf_rtn(v);
                    else
                        ((float*)outp)[(size_t)row * DOUT + col] = v;
                }
                if constexpr (EMITFP8) {
                    unsigned w0 = 0, w1 = 0;
                    w0 = __builtin_amdgcn_cvt_pk_fp8_f32(vv[0] * HSCALE, vv[1] * HSCALE, w0, false);
                    w0 = __builtin_amdgcn_cvt_pk_fp8_f32(vv[2] * HSCALE, vv[3] * HSCALE, w0, true);
                    w1 = __builtin_amdgcn_cvt_pk_fp8_f32(vv[4] * HSCALE, vv[5] * HSCALE, w1, false);
                    w1 = __builtin_amdgcn_cvt_pk_fp8_f32(vv[6] * HSCALE, vv[7] * HSCALE, w1, true);
                    uint2 wq;
                    wq.x = w0;
                    wq.y = w1;
                    ((uint2*)hq)[(size_t)row * 16 + m] = wq;
                }
            }
        }
    }
}

static inline size_t align_up(size_t x, size_t a) { return (x + a - 1) & ~(a - 1); }

extern "C" void kernel_launch(void* const* d_in, const int* in_sizes, int n_in,
                              void* d_out, int out_size, void* d_ws, size_t ws_size,
                              hipStream_t stream) {
    const int N = in_sizes[0] / 128;
    const int E = in_sizes[1] / 2;
    const int NBUCK = (N + BSIZE - 1) >> BSHIFT;

    const float* x = (const float*)d_in[0];
    const int* ei = (const int*)d_in[1];
    const int* src = ei;
    const int* dst = ei + E;
    const float* Wl0 = (const float*)d_in[2];
    const float* bl0 = (const float*)d_in[3];
    const float* Wr0 = (const float*)d_in[4];
    const float* Wl1 = (const float*)d_in[5];
    const float* bl1 = (const float*)d_in[6];
    const float* Wr1 = (const float*)d_in[7];
    const float* Wl2 = (const float*)d_in[8];
    const float* bl2 = (const float*)d_in[9];
    const float* Wr2 = (const float*)d_in[10];
    float* out = (float*)d_out;

    char* w = (char*)d_ws;
    int2* rsdeg = (int2*)w;             w += align_up((size_t)N * 8, 256);
    int* gcntp = (int*)w;               w += align_up((size_t)MAXBUCK * GPAD * 4, 256);
    unsigned* recs = (unsigned*)w;      w += align_up((size_t)NBUCK * CAPB * 4, 256);
    int* srcs = (int*)w;                w += align_up((size_t)NBUCK * CAPB * 4, 256);
    unsigned short* xbf = (unsigned short*)w;  w += align_up((size_t)(N + 1) * 128 * 2, 256);
    unsigned char* xq = (unsigned char*)w;     w += align_up((size_t)(N + 1) * 128, 256);
    unsigned char* hAq = (unsigned char*)w;    w += align_up((size_t)(N + 1) * 128, 256);
    unsigned short* hA = (unsigned short*)w;   w += align_up((size_t)N * 128 * 2, 256);
    unsigned short* hB = (unsigned short*)w;   w += align_up((size_t)N * 128 * 2, 256);
    unsigned short* meanb = (unsigned short*)w; w += align_up((size_t)N * 128 * 2, 256);
    unsigned short* Bp0 = (unsigned short*)w;  w += align_up(8 * 8 * 64 * 8 * 2, 256);
    unsigned short* Bp1 = (unsigned short*)w;  w += align_up(8 * 8 * 64 * 8 * 2, 256);
    unsigned short* Bp2 = (unsigned short*)w;  w += align_up(4 * 8 * 64 * 8 * 2, 256);
    float* bias2 = (float*)w;                  w += align_up(128 * 4, 256);
    unsigned short* z2 = xbf;  // alias: xbf dead after layer-0 gemm; row N stays 0

    const int PB = (N + 4) / 4;  // prep blocks (covers sentinel row N)

    hipMemsetAsync(gcntp, 0, (size_t)MAXBUCK * GPAD * 4, stream);
    partition_edges<<<(E + P1_EDGES - 1) / P1_EDGES, 256, 0, stream>>>(src, dst, E, NBUCK,
                                                                       recs, gcntp);
    prep_all<<<PB + 41, 256, 0, stream>>>(x, xbf, xq, Wl0, Wr0, Wl1, Wr1, Wl2, Wr2, bl2,
                                          Bp0, Bp1, Bp2, bias2, hAq, N, PB);
    build_local_csr<<<NBUCK * 2, 256, 0, stream>>>(recs, gcntp, N, rsdeg, srcs);

    const int aggGrid = (N + 15) / 16;
    const int gemmGrid = (N + 127) / 128;

    // ---- layer 0: agg(x_fp8) -> gemm -> hA bf16 + hAq fp8 ----
    aggregate_fp8<<<aggGrid, 1024, 0, stream>>>(xq, rsdeg, srcs, meanb, N, 1.0f / XSCALE);
    sage_gemm<8, 128, 1, 1, 1, 1><<<gemmGrid, 256, 0, stream>>>(meanb, xbf, Bp0, bl0, hA,
                                                                hAq, N);

    // ---- layer 1: agg(hAq) -> gemm -> hB bf16 ----
    aggregate_fp8<<<aggGrid, 1024, 0, stream>>>(hAq, rsdeg, srcs, meanb, N, 1.0f / HSCALE);
    sage_gemm<8, 128, 1, 1, 1, 0><<<gemmGrid, 256, 0, stream>>>(meanb, hA, Bp1, bl1, hB,
                                                                nullptr, N);

    // ---- layer 2 (commuted): z2 = [hB@Wl2 | hB@Wr2+bl2]; agg left + norm ----
    sage_gemm<4, 128, 0, 0, 1, 0><<<gemmGrid, 256, 0, stream>>>(hB, hB, Bp2, bias2, z2,
                                                                nullptr, N);
    agg64_norm<<<aggGrid, 1024, 0, stream>>>(z2, rsdeg, srcs, out, N);
}